// Round 5
// baseline (865.080 us; speedup 1.0000x reference)
//
#include <hip/hip_runtime.h>
#include <math.h>

typedef unsigned short u16;
typedef unsigned int u32;
typedef __bf16 bfx8 __attribute__((ext_vector_type(8)));
typedef float f32x4 __attribute__((ext_vector_type(4)));

#define NB 16
#define SS 512
#define NHD 16
#define DD 64
#define HD 1024
#define NROWS 8192
#define NEL 8388608  // 8192*1024

// scalar slots in ws (floats)
#define SL_AX_X 0
#define SL_AX_V 1
#define SL_MINSUM 2
#define SL_AX_CTX 3
#define SL_AX_QT 4   // 16 slots
#define SL_AX_KT 20  // 16 slots

struct PLA { float m[12]; float c[12]; float a[12]; };

__device__ __forceinline__ float b2f(u16 u) { return __uint_as_float(((u32)u) << 16); }
// exact for integer-valued floats |x|<=127 (low mantissa bits are zero)
__device__ __forceinline__ u16 f2b_exact(float f) { return (u16)(__float_as_uint(f) >> 16); }
__device__ __forceinline__ float mk_scale(float mx) { float s = mx / 127.0f; return (s == 0.0f) ? 1.0f : s; }
__device__ __forceinline__ float quant_val(float x, float s) {
  return fminf(fmaxf(rintf(x / s), -127.0f), 127.0f);
}
__device__ __forceinline__ float fixclip(float sh) {
  float t = rintf(__fmul_rn(sh, 67108864.0f));          // to_fixed_point frac_bits=26
  float fx = __fmul_rn(t, 1.4901161193847656e-08f);     // exact *2^-26
  return fmaxf(fminf(fx, 0.0f), -10.0f);
}
// fast PLA via uniform-interval guess + 1 correction; tbl[i] = {a[i], a[i+1](or 1e30), m[i], c[i]}
// exactly replicates searchsorted(a, xc, 'right')-1 then m*x+c (separate f32 mul+add)
__device__ __forceinline__ float pla_fast(float xc, const float (*tbl)[4]) {
  int idx = (int)floorf(__fmul_rn(__fadd_rn(xc, 10.0f), 1.2f));
  idx = idx < 0 ? 0 : (idx > 11 ? 11 : idx);
  float4 tv = *(const float4*)tbl[idx];
  int up = (xc >= tv.y) ? 1 : 0;       // never true at idx==11 (sentinel 1e30)
  int dn = (xc < tv.x) ? 1 : 0;        // never true at idx==0 (a[0]=-10 <= xc)
  idx += up - dn;
  float4 tv2 = *(const float4*)tbl[idx];
  return __fadd_rn(__fmul_rn(tv2.z, xc), tv2.w);
}

__global__ void k_init(float* scal) {
  int t = threadIdx.x;
  scal[t] = 0.0f;
  if (t == SL_MINSUM) scal[t] = __uint_as_float(0x7f800000u);  // +inf
}

// per-row absmax + quantize one weight matrix row (fp32) -> integer-valued bf16
__global__ void k_wprep(const float* __restrict__ W, float* __restrict__ sw, u16* __restrict__ wout) {
  int r = blockIdx.x;
  int tid = threadIdx.x;
  float4 v = ((const float4*)(W + (size_t)r * 1024))[tid];
  float m = fmaxf(fmaxf(fabsf(v.x), fabsf(v.y)), fmaxf(fabsf(v.z), fabsf(v.w)));
#pragma unroll
  for (int off = 32; off > 0; off >>= 1) m = fmaxf(m, __shfl_down(m, off));
  __shared__ float red[4];
  __shared__ float sbc;
  int lane = tid & 63, wv = tid >> 6;
  if (lane == 0) red[wv] = m;
  __syncthreads();
  if (tid == 0) sbc = mk_scale(fmaxf(fmaxf(red[0], red[1]), fmaxf(red[2], red[3])));
  __syncthreads();
  float s = sbc;
  if (tid == 0) sw[r] = s;
  u16 o0 = f2b_exact(quant_val(v.x, s));
  u16 o1 = f2b_exact(quant_val(v.y, s));
  u16 o2 = f2b_exact(quant_val(v.z, s));
  u16 o3 = f2b_exact(quant_val(v.w, s));
  u32* orow = (u32*)(wout + (size_t)r * 1024);
  orow[tid * 2] = (u32)o0 | ((u32)o1 << 16);
  orow[tid * 2 + 1] = (u32)o2 | ((u32)o3 << 16);
}

__global__ void k_absmax_f32(const float* __restrict__ x, int n, float* slot) {
  int tid = blockIdx.x * blockDim.x + threadIdx.x;
  int stride = gridDim.x * blockDim.x;
  const float4* x4 = (const float4*)x;
  int n4 = n >> 2;
  float m = 0.f;
  for (int j = tid; j < n4; j += stride) {
    float4 v = x4[j];
    m = fmaxf(m, fmaxf(fmaxf(fabsf(v.x), fabsf(v.y)), fmaxf(fabsf(v.z), fabsf(v.w))));
  }
#pragma unroll
  for (int off = 32; off > 0; off >>= 1) m = fmaxf(m, __shfl_down(m, off));
  __shared__ float red[4];
  if ((threadIdx.x & 63) == 0) red[threadIdx.x >> 6] = m;
  __syncthreads();
  if (threadIdx.x == 0) {
    m = fmaxf(fmaxf(red[0], red[1]), fmaxf(red[2], red[3]));
    atomicMax((u32*)slot, __float_as_uint(m));
  }
}

__global__ void k_quant_f32(const float* __restrict__ x, u16* __restrict__ o, const float* __restrict__ slot) {
  float s = mk_scale(*slot);
  int tid = blockIdx.x * blockDim.x + threadIdx.x;
  int stride = gridDim.x * blockDim.x;
  const float4* x4 = (const float4*)x;
  uint2* o2 = (uint2*)o;
  for (int j = tid; j < (NEL >> 2); j += stride) {
    float4 v = x4[j];
    u16 a = f2b_exact(quant_val(v.x, s));
    u16 b = f2b_exact(quant_val(v.y, s));
    u16 c = f2b_exact(quant_val(v.z, s));
    u16 d = f2b_exact(quant_val(v.w, s));
    uint2 w; w.x = (u32)a | ((u32)b << 16); w.y = (u32)c | ((u32)d << 16);
    o2[j] = w;
  }
}

__global__ void k_quant_tiles(const float* __restrict__ x, u16* __restrict__ o, const float* __restrict__ slots) {
  int tid = blockIdx.x * blockDim.x + threadIdx.x;
  int stride = gridDim.x * blockDim.x;
  const float4* x4 = (const float4*)x;
  uint2* o2 = (uint2*)o;
  for (int j = tid; j < (NEL >> 2); j += stride) {
    int e = j << 2;
    float s = mk_scale(slots[(e >> 11) & 15]);
    float4 v = x4[j];
    u16 a = f2b_exact(quant_val(v.x, s));
    u16 b = f2b_exact(quant_val(v.y, s));
    u16 c = f2b_exact(quant_val(v.z, s));
    u16 d = f2b_exact(quant_val(v.w, s));
    uint2 w; w.x = (u32)a | ((u32)b << 16); w.y = (u32)c | ((u32)d << 16);
    o2[j] = w;
  }
}

// quantize v (global scale) and transpose [B,H,S,D] -> [B,H,D,S]
__global__ void k_quant_vT(const float* __restrict__ x, u16* __restrict__ o, const float* __restrict__ slot) {
  __shared__ u16 lds[64][136];
  float s = mk_scale(*slot);
  int bh = blockIdx.x >> 2;
  int sc0 = (blockIdx.x & 3) << 7;  // 128-row s chunk
  const float4* src = (const float4*)(x + ((size_t)bh * SS + sc0) * DD);
  for (int j = threadIdx.x; j < 2048; j += 256) {
    float4 v = src[j];
    int e = j << 2;
    int srow = e >> 6, d = e & 63;
    lds[d][srow] = f2b_exact(quant_val(v.x, s));
    lds[d + 1][srow] = f2b_exact(quant_val(v.y, s));
    lds[d + 2][srow] = f2b_exact(quant_val(v.z, s));
    lds[d + 3][srow] = f2b_exact(quant_val(v.w, s));
  }
  __syncthreads();
  int d = threadIdx.x >> 2, s0 = (threadIdx.x & 3) << 5;
  u16* dst = o + ((size_t)bh * DD + d) * SS + sc0 + s0;
#pragma unroll
  for (int i = 0; i < 32; i += 8)
    *(uint4*)(dst + i) = *(const uint4*)&lds[d][s0 + i];
}

// C[M,N] = A[M,K] * B[N,K]^T  (both integer-valued bf16; exact in fp32 MFMA accum)
// epilogue: val = acc * (sa*sb[n]) + bias[n]; mode1 -> fp32 [B,NH,S,D]; mode0 -> fp32 [M,N]
// axmode: 0 none; 1 per-seq-tile absmax atomics into axslots[16]; 2 global absmax into axslots[0]
__global__ __launch_bounds__(256) void k_gemm(const u16* __restrict__ A, const u16* __restrict__ Bw,
    const float* __restrict__ axslot, const float* __restrict__ sb, const float* __restrict__ bias,
    float* outf, float* outc, int mode, float* axslots, int axmode) {
  __shared__ u16 As[128][72];
  __shared__ u16 Bs[128][72];
  int tid = threadIdx.x;
  int bm = blockIdx.x << 7, bn = blockIdx.y << 7;
  int wv = tid >> 6, lane = tid & 63, quad = lane >> 4, l16 = lane & 15;
  int wr = (wv >> 1) << 6, wc = (wv & 1) << 6;
  int sr = tid >> 1, sseg = (tid & 1) << 5;
  const u16* Ag = A + (size_t)(bm + sr) * 1024 + sseg;
  const u16* Bg = Bw + (size_t)(bn + sr) * 1024 + sseg;
  f32x4 zero = {0.f, 0.f, 0.f, 0.f};
  f32x4 acc[4][4];
#pragma unroll
  for (int i = 0; i < 4; i++)
#pragma unroll
    for (int j = 0; j < 4; j++) acc[i][j] = zero;
  for (int k0 = 0; k0 < 1024; k0 += 64) {
    uint4 av0 = *(const uint4*)(Ag + k0);
    uint4 av1 = *(const uint4*)(Ag + k0 + 8);
    uint4 av2 = *(const uint4*)(Ag + k0 + 16);
    uint4 av3 = *(const uint4*)(Ag + k0 + 24);
    uint4 bv0 = *(const uint4*)(Bg + k0);
    uint4 bv1 = *(const uint4*)(Bg + k0 + 8);
    uint4 bv2 = *(const uint4*)(Bg + k0 + 16);
    uint4 bv3 = *(const uint4*)(Bg + k0 + 24);
    __syncthreads();
    *(uint4*)&As[sr][sseg] = av0;      *(uint4*)&As[sr][sseg + 8] = av1;
    *(uint4*)&As[sr][sseg + 16] = av2; *(uint4*)&As[sr][sseg + 24] = av3;
    *(uint4*)&Bs[sr][sseg] = bv0;      *(uint4*)&Bs[sr][sseg + 8] = bv1;
    *(uint4*)&Bs[sr][sseg + 16] = bv2; *(uint4*)&Bs[sr][sseg + 24] = bv3;
    __syncthreads();
#pragma unroll
    for (int ks = 0; ks < 2; ks++) {
      bfx8 af[4], bfr[4];
#pragma unroll
      for (int i = 0; i < 4; i++) {
        af[i] = *(const bfx8*)&As[wr + i * 16 + l16][ks * 32 + quad * 8];
        bfr[i] = *(const bfx8*)&Bs[wc + i * 16 + l16][ks * 32 + quad * 8];
      }
#pragma unroll
      for (int i = 0; i < 4; i++)
#pragma unroll
        for (int j = 0; j < 4; j++)
          acc[i][j] = __builtin_amdgcn_mfma_f32_16x16x32_bf16(af[i], bfr[j], acc[i][j], 0, 0, 0);
    }
  }
  float sa = mk_scale(*axslot);
  float amax[4] = {0.f, 0.f, 0.f, 0.f};
#pragma unroll
  for (int j = 0; j < 4; j++) {
    int col = bn + wc + j * 16 + l16;
    float sc = __fmul_rn(sa, sb[col]);
    float bi = bias[col];
#pragma unroll
    for (int i = 0; i < 4; i++) {
      int row0 = bm + wr + i * 16 + quad * 4;
#pragma unroll
      for (int r = 0; r < 4; r++) {
        float v = __fadd_rn(__fmul_rn(acc[i][j][r], sc), bi);
        amax[i] = fmaxf(amax[i], fabsf(v));
        int row = row0 + r;
        if (mode) {
          int b = row >> 9, s2 = row & 511, h = col >> 6, d = col & 63;
          outf[((((size_t)b * NHD) + h) * SS + s2) * DD + d] = v;
        } else {
          outc[(size_t)row * HD + col] = v;
        }
      }
    }
  }
  if (axmode == 1) {
    int stile_base = (bm & 511) >> 5;
#pragma unroll
    for (int i = 0; i < 4; i++) {
      float am = amax[i];
#pragma unroll
      for (int m2 = 1; m2 < 64; m2 <<= 1) am = fmaxf(am, __shfl_xor(am, m2));
      if (lane == 0)
        atomicMax((u32*)&axslots[stile_base + ((wr + i * 16) >> 5)], __float_as_uint(am));
    }
  } else if (axmode == 2) {
    float am = fmaxf(fmaxf(amax[0], amax[1]), fmaxf(amax[2], amax[3]));
#pragma unroll
    for (int m2 = 1; m2 < 64; m2 <<= 1) am = fmaxf(am, __shfl_xor(am, m2));
    if (lane == 0) atomicMax((u32*)axslots, __float_as_uint(am));
  }
}

// pass 1: rowmax + PLA row sums in ONE pass (scores held in registers), K staged in LDS halves.
// grid (bh=256, qtile=8): linear id = bh + 256*q -> XCD = bh%8 (K reuse within one XCD's L2)
__global__ __launch_bounds__(256, 2) void k_attn1(const u16* __restrict__ qq, const u16* __restrict__ kq,
    const float* __restrict__ scal, float* __restrict__ minslot,
    float* __restrict__ rowmax, float* __restrict__ rowsum, PLA pla) {
  __shared__ u16 Ks[256][72];        // 36 KB: half of K (256 rows x 64), padded stride
  __shared__ float tbl[12][4];       // {a[i], a[i+1]|1e30, m[i], c[i]}
  __shared__ float redmin[4];
  int tid = threadIdx.x;
  if (tid < 12) {
    tbl[tid][0] = pla.a[tid];
    tbl[tid][1] = (tid < 11) ? pla.a[tid + 1] : 1e30f;
    tbl[tid][2] = pla.m[tid];
    tbl[tid][3] = pla.c[tid];
  }
  int bh = blockIdx.x;
  int q0 = blockIdx.y << 6;
  int wv = tid >> 6, lane = tid & 63, quad = lane >> 4, l16 = lane & 15;
  int rowb = q0 + wv * 16;
  const u16* qbase = qq + ((size_t)bh * SS + rowb) * DD;
  const u16* kg = kq + (size_t)bh * SS * DD;
  bfx8 a0 = *(const bfx8*)(qbase + l16 * DD + quad * 8);
  bfx8 a1 = *(const bfx8*)(qbase + l16 * DD + 32 + quad * 8);
  float sqv = mk_scale(scal[SL_AX_QT + (rowb >> 5)]);
  f32x4 sreg[32];
  float rm[4] = {-INFINITY, -INFINITY, -INFINITY, -INFINITY};
#pragma unroll
  for (int half = 0; half < 2; half++) {
    __syncthreads();
    for (int j = tid; j < 2048; j += 256) {
      int row = j >> 3, seg = (j & 7) * 8;
      *(uint4*)&Ks[row][seg] = *(const uint4*)(kg + (half * 256 + row) * 64 + seg);
    }
    __syncthreads();
#pragma unroll
    for (int t = 0; t < 8; t++) {
      float sk = mk_scale(scal[SL_AX_KT + half * 8 + t]);
      float sc = __fmul_rn(__fmul_rn(0.125f, sqv), sk);
#pragma unroll
      for (int h = 0; h < 2; h++) {
        int cbl = t * 2 + h;
        bfx8 b0 = *(const bfx8*)&Ks[cbl * 16 + l16][quad * 8];
        bfx8 b1 = *(const bfx8*)&Ks[cbl * 16 + l16][32 + quad * 8];
        f32x4 acc = {0.f, 0.f, 0.f, 0.f};
        acc = __builtin_amdgcn_mfma_f32_16x16x32_bf16(a0, b0, acc, 0, 0, 0);
        acc = __builtin_amdgcn_mfma_f32_16x16x32_bf16(a1, b1, acc, 0, 0, 0);
        int cb = half * 16 + cbl;
#pragma unroll
        for (int r = 0; r < 4; r++) {
          float sv_ = __fmul_rn(acc[r], sc);
          sreg[cb][r] = sv_;
          rm[r] = fmaxf(rm[r], sv_);
        }
      }
    }
  }
#pragma unroll
  for (int m = 1; m < 16; m <<= 1)
#pragma unroll
    for (int r = 0; r < 4; r++) rm[r] = fmaxf(rm[r], __shfl_xor(rm[r], m));
  float sums[4] = {0.f, 0.f, 0.f, 0.f};
#pragma unroll
  for (int cb = 0; cb < 32; cb++)
#pragma unroll
    for (int r = 0; r < 4; r++) {
      float xc = fixclip(__fsub_rn(sreg[cb][r], rm[r]));
      sums[r] = __fadd_rn(sums[r], pla_fast(xc, tbl));
    }
#pragma unroll
  for (int m = 1; m < 16; m <<= 1)
#pragma unroll
    for (int r = 0; r < 4; r++) sums[r] += __shfl_xor(sums[r], m);
  if (l16 == 0) {
#pragma unroll
    for (int r = 0; r < 4; r++) {
      int row = bh * SS + rowb + quad * 4 + r;
      rowmax[row] = rm[r];
      rowsum[row] = sums[r];
    }
  }
  // one atomicMin per block
  float mn = fminf(fminf(sums[0], sums[1]), fminf(sums[2], sums[3]));
#pragma unroll
  for (int m = 16; m < 64; m <<= 1) mn = fminf(mn, __shfl_xor(mn, m));
  if (lane == 0) redmin[wv] = mn;
  __syncthreads();
  if (tid == 0) {
    mn = fminf(fminf(redmin[0], redmin[1]), fminf(redmin[2], redmin[3]));
    atomicMin((u32*)minslot, __float_as_uint(mn));
  }
}

// pass 2: recompute scores, quantize probs (per-row reciprocal, no per-element div), PV,
// write ctx fp32 [B,S,H*D] + fused ctx global absmax. grid (bh=256, qtile=16).
__global__ __launch_bounds__(256) void k_attn2(const u16* __restrict__ qq, const u16* __restrict__ kq,
    const u16* __restrict__ vqt, const float* __restrict__ scal, const float* __restrict__ rowmax,
    const float* __restrict__ rowsum, float* __restrict__ ctx, float* __restrict__ ctxax, PLA pla) {
  __shared__ u16 P[32][520];
  __shared__ float tbl[12][4];
  int tid = threadIdx.x;
  if (tid < 12) {
    tbl[tid][0] = pla.a[tid];
    tbl[tid][1] = (tid < 11) ? pla.a[tid + 1] : 1e30f;
    tbl[tid][2] = pla.m[tid];
    tbl[tid][3] = pla.c[tid];
  }
  __syncthreads();
  int bh = blockIdx.x;
  int q0 = blockIdx.y << 5;
  int wv = tid >> 6, lane = tid & 63, quad = lane >> 4, l16 = lane & 15;
  int rb = (wv >> 1) * 16;
  int cb0 = (wv & 1) * 16;
  const u16* qbase = qq + ((size_t)bh * SS + q0 + rb) * DD;
  const u16* kbase = kq + (size_t)bh * SS * DD;
  bfx8 a0 = *(const bfx8*)(qbase + l16 * DD + quad * 8);
  bfx8 a1 = *(const bfx8*)(qbase + l16 * DD + 32 + quad * 8);
  float sqv = mk_scale(scal[SL_AX_QT + (q0 >> 5)]);
  float minsum = scal[SL_MINSUM];
  float mxsm = pla.c[11] / (minsum + 1e-9f);   // == global max(sm): PLA monotone, every row attains x=0
  float scp = mk_scale(mxsm);
  float rmx[4], inv[4];
#pragma unroll
  for (int r = 0; r < 4; r++) {
    int row = bh * SS + q0 + rb + quad * 4 + r;
    rmx[r] = rowmax[row];
    float t = __fmul_rn(rowsum[row] + 1e-9f, scp);
    inv[r] = 1.0f / t;   // fused (e/rsm)/scp -> e*inv; <=3ulp difference, rint flip ~1e-6/elem
  }
#pragma unroll
  for (int t = 0; t < 8; t++) {
    float sk = mk_scale(scal[SL_AX_KT + (cb0 >> 1) + t]);
    float sc = __fmul_rn(__fmul_rn(0.125f, sqv), sk);
#pragma unroll
    for (int h = 0; h < 2; h++) {
      int cb = cb0 + t * 2 + h;
      const u16* kp = kbase + (size_t)(cb * 16 + l16) * DD + quad * 8;
      bfx8 b0 = *(const bfx8*)kp;
      bfx8 b1 = *(const bfx8*)(kp + 32);
      f32x4 acc = {0.f, 0.f, 0.f, 0.f};
      acc = __builtin_amdgcn_mfma_f32_16x16x32_bf16(a0, b0, acc, 0, 0, 0);
      acc = __builtin_amdgcn_mfma_f32_16x16x32_bf16(a1, b1, acc, 0, 0, 0);
#pragma unroll
      for (int r = 0; r < 4; r++) {
        float sh = __fsub_rn(__fmul_rn(acc[r], sc), rmx[r]);
        float e = pla_fast(fixclip(sh), tbl);
        float np = fminf(fmaxf(rintf(__fmul_rn(e, inv[r])), -127.0f), 127.0f);
        P[rb + quad * 4 + r][cb * 16 + l16] = f2b_exact(np);
      }
    }
  }
  __syncthreads();
  f32x4 acc2[2];
  f32x4 zero = {0.f, 0.f, 0.f, 0.f};
  acc2[0] = zero; acc2[1] = zero;
  const u16* vb = vqt + (size_t)bh * DD * SS;
  int dbase = (wv & 1) * 32;
  int rb2 = (wv >> 1) * 16;
  for (int ks = 0; ks < 16; ks++) {
    bfx8 pa = *(const bfx8*)&P[rb2 + l16][ks * 32 + quad * 8];
#pragma unroll
    for (int j = 0; j < 2; j++) {
      int d = dbase + j * 16 + l16;
      bfx8 vf = *(const bfx8*)(vb + (size_t)d * SS + ks * 32 + quad * 8);
      acc2[j] = __builtin_amdgcn_mfma_f32_16x16x32_bf16(pa, vf, acc2[j], 0, 0, 0);
    }
  }
  float sv = mk_scale(scal[SL_AX_V]);
  float fsc = __fmul_rn(scp, sv);
  int b = bh >> 4, h = bh & 15;
  float cmax = 0.f;
#pragma unroll
  for (int j = 0; j < 2; j++) {
    int d = dbase + j * 16 + l16;
#pragma unroll
    for (int r = 0; r < 4; r++) {
      int srow = q0 + rb2 + quad * 4 + r;
      float cv = __fmul_rn(acc2[j][r], fsc);
      cmax = fmaxf(cmax, fabsf(cv));
      ctx[((size_t)(b * SS + srow)) * HD + h * DD + d] = cv;
    }
  }
#pragma unroll
  for (int m2 = 1; m2 < 64; m2 <<= 1) cmax = fmaxf(cmax, __shfl_xor(cmax, m2));
  if (lane == 0) atomicMax((u32*)ctxax, __float_as_uint(cmax));
}

// host: rebuild _build_pla exactly (float64 linspace mirror + degree-1 OLS, cast to f32)
static void build_pla(PLA* p) {
  double xs[1001], ys[1001];
  for (int i = 0; i < 1001; i++) { double t = (double)i * 0.01; xs[i] = t - 10.0; }
  xs[1000] = 0.0;
  for (int i = 0; i < 1001; i++) ys[i] = exp(xs[i]);
  double es = 10.0 / 12.0;
  double edges[13];
  for (int i = 0; i < 13; i++) { double t = (double)i * es; edges[i] = t - 10.0; }
  edges[12] = 0.0;
  for (int k = 0; k < 12; k++) {
    double sx = 0, sy = 0, sxx = 0, sxy = 0; int n = 0;
    for (int j = 0; j < 1001; j++) {
      if (xs[j] >= edges[k] && xs[j] <= edges[k + 1]) {
        n++; sx += xs[j]; sy += ys[j]; sxx += xs[j] * xs[j]; sxy += xs[j] * ys[j];
      }
    }
    double mx = sx / n, my = sy / n;
    double mm = (sxy - sx * my) / (sxx - sx * mx);
    double cc = my - mm * mx;
    p->m[k] = (float)mm; p->c[k] = (float)cc; p->a[k] = (float)edges[k];
  }
}

extern "C" void kernel_launch(void* const* d_in, const int* in_sizes, int n_in,
                              void* d_out, int out_size, void* d_ws, size_t ws_size,
                              hipStream_t stream) {
  const float* hs = (const float*)d_in[0];
  const float* Wq = (const float*)d_in[1]; const float* bq = (const float*)d_in[2];
  const float* Wk = (const float*)d_in[3]; const float* bk = (const float*)d_in[4];
  const float* Wv = (const float*)d_in[5]; const float* bv = (const float*)d_in[6];
  const float* Wo = (const float*)d_in[7]; const float* bo = (const float*)d_in[8];
  float* out = (float*)d_out;
  char* ws = (char*)d_ws;
  float* scal = (float*)ws;                         // 64 scalar slots
  float* sw = (float*)(ws + 4096);                  // 4*1024 per-row weight scales
  float* rowmax = (float*)(ws + (64 << 10));        // 131072 f32
  float* rowsum = (float*)(ws + (576 << 10));       // 131072 f32
  u16* wb = (u16*)(ws + (2ll << 20));               // 4 x [1024,1024] bf16-int
  u16* xq = (u16*)(ws + (10ll << 20));              // [8192,1024] bf16-int (later reused as ctxq)
  u16* qq = (u16*)(ws + (26ll << 20));              // [B,H,S,D]
  u16* kq = (u16*)(ws + (42ll << 20));              // [B,H,S,D]
  u16* vqt = (u16*)(ws + (58ll << 20));             // [B,H,D,S]
  float* tmp = (float*)(ws + (74ll << 20));         // [8192,1024] fp32 temp (q/k/v then ctx)
  u16* ctxq = xq;

  PLA pla;
  build_pla(&pla);

  k_init<<<1, 64, 0, stream>>>(scal);
  k_wprep<<<1024, 256, 0, stream>>>(Wq, sw + 0, wb + 0);
  k_wprep<<<1024, 256, 0, stream>>>(Wk, sw + 1024, wb + 1048576);
  k_wprep<<<1024, 256, 0, stream>>>(Wv, sw + 2048, wb + 2097152);
  k_wprep<<<1024, 256, 0, stream>>>(Wo, sw + 3072, wb + 3145728);
  k_absmax_f32<<<512, 256, 0, stream>>>(hs, NEL, scal + SL_AX_X);
  k_quant_f32<<<1024, 256, 0, stream>>>(hs, xq, scal + SL_AX_X);

  const float* biases[3] = {bq, bk, bv};
  for (int z = 0; z < 3; z++) {
    int axmode = (z < 2) ? 1 : 2;
    float* axslots = (z == 0) ? (scal + SL_AX_QT) : (z == 1) ? (scal + SL_AX_KT) : (scal + SL_AX_V);
    k_gemm<<<dim3(64, 8), 256, 0, stream>>>(xq, wb + (size_t)z * 1048576, scal + SL_AX_X,
                                            sw + z * 1024, biases[z], tmp, (float*)0, 1,
                                            axslots, axmode);
    if (z == 0) {
      k_quant_tiles<<<1024, 256, 0, stream>>>(tmp, qq, scal + SL_AX_QT);
    } else if (z == 1) {
      k_quant_tiles<<<1024, 256, 0, stream>>>(tmp, kq, scal + SL_AX_KT);
    } else {
      k_quant_vT<<<1024, 256, 0, stream>>>(tmp, vqt, scal + SL_AX_V);
    }
  }

  k_attn1<<<dim3(256, 8), 256, 0, stream>>>(qq, kq, scal, scal + SL_MINSUM, rowmax, rowsum, pla);
  k_attn2<<<dim3(256, 16), 256, 0, stream>>>(qq, kq, vqt, scal, rowmax, rowsum, tmp,
                                             scal + SL_AX_CTX, pla);

  k_quant_f32<<<1024, 256, 0, stream>>>(tmp, ctxq, scal + SL_AX_CTX);
  k_gemm<<<dim3(64, 8), 256, 0, stream>>>(ctxq, wb + 3145728, scal + SL_AX_CTX,
                                          sw + 3072, bo, (float*)0, out, 0,
                                          (float*)0, 0);
}

// Round 6
// 763.760 us; speedup vs baseline: 1.1327x; 1.1327x over previous
//
#include <hip/hip_runtime.h>
#include <math.h>

typedef unsigned short u16;
typedef unsigned int u32;
typedef __bf16 bfx8 __attribute__((ext_vector_type(8)));
typedef float f32x4 __attribute__((ext_vector_type(4)));

#define NB 16
#define SS 512
#define NHD 16
#define DD 64
#define HD 1024
#define NROWS 8192
#define NEL 8388608  // 8192*1024

// scalar slots in ws (floats)
#define SL_AX_X 0
#define SL_AX_V 1
#define SL_MINSUM 2
#define SL_AX_CTX 3
#define SL_AX_QT 4    // 16 slots
#define SL_AX_KT 20   // 16 slots
#define SL_AX_CTX8 36 // 8 slots (decontended ctx absmax)

struct PLA { float m[12]; float c[12]; float a[12]; };

__device__ __forceinline__ float b2f(u16 u) { return __uint_as_float(((u32)u) << 16); }
// exact for integer-valued floats |x|<=127 (low mantissa bits are zero)
__device__ __forceinline__ u16 f2b_exact(float f) { return (u16)(__float_as_uint(f) >> 16); }
__device__ __forceinline__ float mk_scale(float mx) { float s = mx / 127.0f; return (s == 0.0f) ? 1.0f : s; }
__device__ __forceinline__ float quant_val(float x, float s) {
  return fminf(fmaxf(rintf(x / s), -127.0f), 127.0f);
}
__device__ __forceinline__ float fixclip(float sh) {
  float t = rintf(__fmul_rn(sh, 67108864.0f));          // to_fixed_point frac_bits=26
  float fx = __fmul_rn(t, 1.4901161193847656e-08f);     // exact *2^-26
  return fmaxf(fminf(fx, 0.0f), -10.0f);
}
// fast PLA via uniform-interval guess + 1 correction; tbl[i] = {a[i], a[i+1](or 1e30), m[i], c[i]}
// exactly replicates searchsorted(a, xc, 'right')-1 then m*x+c (separate f32 mul+add)
__device__ __forceinline__ float pla_fast(float xc, const float (*tbl)[4]) {
  int idx = (int)floorf(__fmul_rn(__fadd_rn(xc, 10.0f), 1.2f));
  idx = idx < 0 ? 0 : (idx > 11 ? 11 : idx);
  float4 tv = *(const float4*)tbl[idx];
  int up = (xc >= tv.y) ? 1 : 0;       // never true at idx==11 (sentinel 1e30)
  int dn = (xc < tv.x) ? 1 : 0;        // never true at idx==0 (a[0]=-10 <= xc)
  idx += up - dn;
  float4 tv2 = *(const float4*)tbl[idx];
  return __fadd_rn(__fmul_rn(tv2.z, xc), tv2.w);
}

__global__ void k_init(float* scal) {
  int t = threadIdx.x;
  scal[t] = 0.0f;
  if (t == SL_MINSUM) scal[t] = __uint_as_float(0x7f800000u);  // +inf
}

// per-row absmax + quantize one weight matrix row (fp32) -> integer-valued bf16
__global__ void k_wprep(const float* __restrict__ W, float* __restrict__ sw, u16* __restrict__ wout) {
  int r = blockIdx.x;
  int tid = threadIdx.x;
  float4 v = ((const float4*)(W + (size_t)r * 1024))[tid];
  float m = fmaxf(fmaxf(fabsf(v.x), fabsf(v.y)), fmaxf(fabsf(v.z), fabsf(v.w)));
#pragma unroll
  for (int off = 32; off > 0; off >>= 1) m = fmaxf(m, __shfl_down(m, off));
  __shared__ float red[4];
  __shared__ float sbc;
  int lane = tid & 63, wv = tid >> 6;
  if (lane == 0) red[wv] = m;
  __syncthreads();
  if (tid == 0) sbc = mk_scale(fmaxf(fmaxf(red[0], red[1]), fmaxf(red[2], red[3])));
  __syncthreads();
  float s = sbc;
  if (tid == 0) sw[r] = s;
  u16 o0 = f2b_exact(quant_val(v.x, s));
  u16 o1 = f2b_exact(quant_val(v.y, s));
  u16 o2 = f2b_exact(quant_val(v.z, s));
  u16 o3 = f2b_exact(quant_val(v.w, s));
  u32* orow = (u32*)(wout + (size_t)r * 1024);
  orow[tid * 2] = (u32)o0 | ((u32)o1 << 16);
  orow[tid * 2 + 1] = (u32)o2 | ((u32)o3 << 16);
}

__global__ void k_absmax_f32(const float* __restrict__ x, int n, float* slot) {
  int tid = blockIdx.x * blockDim.x + threadIdx.x;
  int stride = gridDim.x * blockDim.x;
  const float4* x4 = (const float4*)x;
  int n4 = n >> 2;
  float m = 0.f;
  for (int j = tid; j < n4; j += stride) {
    float4 v = x4[j];
    m = fmaxf(m, fmaxf(fmaxf(fabsf(v.x), fabsf(v.y)), fmaxf(fabsf(v.z), fabsf(v.w))));
  }
#pragma unroll
  for (int off = 32; off > 0; off >>= 1) m = fmaxf(m, __shfl_down(m, off));
  __shared__ float red[4];
  if ((threadIdx.x & 63) == 0) red[threadIdx.x >> 6] = m;
  __syncthreads();
  if (threadIdx.x == 0) {
    m = fmaxf(fmaxf(red[0], red[1]), fmaxf(red[2], red[3]));
    atomicMax((u32*)slot, __float_as_uint(m));
  }
}

__global__ void k_quant_f32(const float* __restrict__ x, u16* __restrict__ o, const float* __restrict__ slot) {
  float s = mk_scale(*slot);
  int tid = blockIdx.x * blockDim.x + threadIdx.x;
  int stride = gridDim.x * blockDim.x;
  const float4* x4 = (const float4*)x;
  uint2* o2 = (uint2*)o;
  for (int j = tid; j < (NEL >> 2); j += stride) {
    float4 v = x4[j];
    u16 a = f2b_exact(quant_val(v.x, s));
    u16 b = f2b_exact(quant_val(v.y, s));
    u16 c = f2b_exact(quant_val(v.z, s));
    u16 d = f2b_exact(quant_val(v.w, s));
    uint2 w; w.x = (u32)a | ((u32)b << 16); w.y = (u32)c | ((u32)d << 16);
    o2[j] = w;
  }
}

// ctx quant: scale from max of 8 decontended slots; republish folded max for the final gemm
__global__ void k_quant_ctx(const float* __restrict__ x, u16* __restrict__ o,
                            const float* __restrict__ slots8, float* __restrict__ axout) {
  float mx = 0.f;
#pragma unroll
  for (int i = 0; i < 8; i++) mx = fmaxf(mx, slots8[i]);
  float s = mk_scale(mx);
  if (blockIdx.x == 0 && threadIdx.x == 0) *axout = mx;
  int tid = blockIdx.x * blockDim.x + threadIdx.x;
  int stride = gridDim.x * blockDim.x;
  const float4* x4 = (const float4*)x;
  uint2* o2 = (uint2*)o;
  for (int j = tid; j < (NEL >> 2); j += stride) {
    float4 v = x4[j];
    u16 a = f2b_exact(quant_val(v.x, s));
    u16 b = f2b_exact(quant_val(v.y, s));
    u16 c = f2b_exact(quant_val(v.z, s));
    u16 d = f2b_exact(quant_val(v.w, s));
    uint2 w; w.x = (u32)a | ((u32)b << 16); w.y = (u32)c | ((u32)d << 16);
    o2[j] = w;
  }
}

__global__ void k_quant_tiles(const float* __restrict__ x, u16* __restrict__ o, const float* __restrict__ slots) {
  int tid = blockIdx.x * blockDim.x + threadIdx.x;
  int stride = gridDim.x * blockDim.x;
  const float4* x4 = (const float4*)x;
  uint2* o2 = (uint2*)o;
  for (int j = tid; j < (NEL >> 2); j += stride) {
    int e = j << 2;
    float s = mk_scale(slots[(e >> 11) & 15]);
    float4 v = x4[j];
    u16 a = f2b_exact(quant_val(v.x, s));
    u16 b = f2b_exact(quant_val(v.y, s));
    u16 c = f2b_exact(quant_val(v.z, s));
    u16 d = f2b_exact(quant_val(v.w, s));
    uint2 w; w.x = (u32)a | ((u32)b << 16); w.y = (u32)c | ((u32)d << 16);
    o2[j] = w;
  }
}

// quantize v (global scale) and transpose [B,H,S,D] -> [B,H,D,S]
__global__ void k_quant_vT(const float* __restrict__ x, u16* __restrict__ o, const float* __restrict__ slot) {
  __shared__ u16 lds[64][136];
  float s = mk_scale(*slot);
  int bh = blockIdx.x >> 2;
  int sc0 = (blockIdx.x & 3) << 7;  // 128-row s chunk
  const float4* src = (const float4*)(x + ((size_t)bh * SS + sc0) * DD);
  for (int j = threadIdx.x; j < 2048; j += 256) {
    float4 v = src[j];
    int e = j << 2;
    int srow = e >> 6, d = e & 63;
    lds[d][srow] = f2b_exact(quant_val(v.x, s));
    lds[d + 1][srow] = f2b_exact(quant_val(v.y, s));
    lds[d + 2][srow] = f2b_exact(quant_val(v.z, s));
    lds[d + 3][srow] = f2b_exact(quant_val(v.w, s));
  }
  __syncthreads();
  int d = threadIdx.x >> 2, s0 = (threadIdx.x & 3) << 5;
  u16* dst = o + ((size_t)bh * DD + d) * SS + sc0 + s0;
#pragma unroll
  for (int i = 0; i < 32; i += 8)
    *(uint4*)(dst + i) = *(const uint4*)&lds[d][s0 + i];
}

// C[M,N] = A[M,K] * B[N,K]^T  (both integer-valued bf16; exact in fp32 MFMA accum)
// epilogue: val = acc * (sa*sb[n]) + bias[n]; mode1 -> fp32 [B,NH,S,D]; mode0 -> fp32 [M,N]
// axmode: 0 none; 1 per-seq-tile absmax atomics into axslots[16]; 2 global absmax into axslots[0]
__global__ __launch_bounds__(256) void k_gemm(const u16* __restrict__ A, const u16* __restrict__ Bw,
    const float* __restrict__ axslot, const float* __restrict__ sb, const float* __restrict__ bias,
    float* outf, float* outc, int mode, float* axslots, int axmode) {
  __shared__ u16 As[128][72];
  __shared__ u16 Bs[128][72];
  int tid = threadIdx.x;
  int bm = blockIdx.x << 7, bn = blockIdx.y << 7;
  int wv = tid >> 6, lane = tid & 63, quad = lane >> 4, l16 = lane & 15;
  int wr = (wv >> 1) << 6, wc = (wv & 1) << 6;
  int sr = tid >> 1, sseg = (tid & 1) << 5;
  const u16* Ag = A + (size_t)(bm + sr) * 1024 + sseg;
  const u16* Bg = Bw + (size_t)(bn + sr) * 1024 + sseg;
  f32x4 zero = {0.f, 0.f, 0.f, 0.f};
  f32x4 acc[4][4];
#pragma unroll
  for (int i = 0; i < 4; i++)
#pragma unroll
    for (int j = 0; j < 4; j++) acc[i][j] = zero;
  for (int k0 = 0; k0 < 1024; k0 += 64) {
    uint4 av0 = *(const uint4*)(Ag + k0);
    uint4 av1 = *(const uint4*)(Ag + k0 + 8);
    uint4 av2 = *(const uint4*)(Ag + k0 + 16);
    uint4 av3 = *(const uint4*)(Ag + k0 + 24);
    uint4 bv0 = *(const uint4*)(Bg + k0);
    uint4 bv1 = *(const uint4*)(Bg + k0 + 8);
    uint4 bv2 = *(const uint4*)(Bg + k0 + 16);
    uint4 bv3 = *(const uint4*)(Bg + k0 + 24);
    __syncthreads();
    *(uint4*)&As[sr][sseg] = av0;      *(uint4*)&As[sr][sseg + 8] = av1;
    *(uint4*)&As[sr][sseg + 16] = av2; *(uint4*)&As[sr][sseg + 24] = av3;
    *(uint4*)&Bs[sr][sseg] = bv0;      *(uint4*)&Bs[sr][sseg + 8] = bv1;
    *(uint4*)&Bs[sr][sseg + 16] = bv2; *(uint4*)&Bs[sr][sseg + 24] = bv3;
    __syncthreads();
#pragma unroll
    for (int ks = 0; ks < 2; ks++) {
      bfx8 af[4], bfr[4];
#pragma unroll
      for (int i = 0; i < 4; i++) {
        af[i] = *(const bfx8*)&As[wr + i * 16 + l16][ks * 32 + quad * 8];
        bfr[i] = *(const bfx8*)&Bs[wc + i * 16 + l16][ks * 32 + quad * 8];
      }
#pragma unroll
      for (int i = 0; i < 4; i++)
#pragma unroll
        for (int j = 0; j < 4; j++)
          acc[i][j] = __builtin_amdgcn_mfma_f32_16x16x32_bf16(af[i], bfr[j], acc[i][j], 0, 0, 0);
    }
  }
  float sa = mk_scale(*axslot);
  float amax[4] = {0.f, 0.f, 0.f, 0.f};
#pragma unroll
  for (int j = 0; j < 4; j++) {
    int col = bn + wc + j * 16 + l16;
    float sc = __fmul_rn(sa, sb[col]);
    float bi = bias[col];
#pragma unroll
    for (int i = 0; i < 4; i++) {
      int row0 = bm + wr + i * 16 + quad * 4;
#pragma unroll
      for (int r = 0; r < 4; r++) {
        float v = __fadd_rn(__fmul_rn(acc[i][j][r], sc), bi);
        amax[i] = fmaxf(amax[i], fabsf(v));
        int row = row0 + r;
        if (mode) {
          int b = row >> 9, s2 = row & 511, h = col >> 6, d = col & 63;
          outf[((((size_t)b * NHD) + h) * SS + s2) * DD + d] = v;
        } else {
          outc[(size_t)row * HD + col] = v;
        }
      }
    }
  }
  if (axmode == 1) {
    int stile_base = (bm & 511) >> 5;
#pragma unroll
    for (int i = 0; i < 4; i++) {
      float am = amax[i];
#pragma unroll
      for (int m2 = 1; m2 < 64; m2 <<= 1) am = fmaxf(am, __shfl_xor(am, m2));
      if (lane == 0)
        atomicMax((u32*)&axslots[stile_base + ((wr + i * 16) >> 5)], __float_as_uint(am));
    }
  } else if (axmode == 2) {
    float am = fmaxf(fmaxf(amax[0], amax[1]), fmaxf(amax[2], amax[3]));
#pragma unroll
    for (int m2 = 1; m2 < 64; m2 <<= 1) am = fmaxf(am, __shfl_xor(am, m2));
    if (lane == 0) atomicMax((u32*)axslots, __float_as_uint(am));
  }
}

// pass 1: rowmax + PLA row sums in ONE pass (scores held in registers), K staged in LDS halves.
// linear bh-major grid: consecutive blocks share bh -> small concurrent working set per XCD
__global__ __launch_bounds__(256, 2) void k_attn1(const u16* __restrict__ qq, const u16* __restrict__ kq,
    const float* __restrict__ scal, float* __restrict__ minslot,
    float* __restrict__ rowmax, float* __restrict__ rowsum, PLA pla) {
  __shared__ u16 Ks[256][72];        // 36 KB: half of K (256 rows x 64), padded stride
  __shared__ float tbl[12][4];       // {a[i], a[i+1]|1e30, m[i], c[i]}
  __shared__ float redmin[4];
  int tid = threadIdx.x;
  if (tid < 12) {
    tbl[tid][0] = pla.a[tid];
    tbl[tid][1] = (tid < 11) ? pla.a[tid + 1] : 1e30f;
    tbl[tid][2] = pla.m[tid];
    tbl[tid][3] = pla.c[tid];
  }
  int bh = blockIdx.x >> 3;
  int q0 = (blockIdx.x & 7) << 6;
  int wv = tid >> 6, lane = tid & 63, quad = lane >> 4, l16 = lane & 15;
  int rowb = q0 + wv * 16;
  const u16* qbase = qq + ((size_t)bh * SS + rowb) * DD;
  const u16* kg = kq + (size_t)bh * SS * DD;
  bfx8 a0 = *(const bfx8*)(qbase + l16 * DD + quad * 8);
  bfx8 a1 = *(const bfx8*)(qbase + l16 * DD + 32 + quad * 8);
  float sqv = mk_scale(scal[SL_AX_QT + (rowb >> 5)]);
  f32x4 sreg[32];
  float rm[4] = {-INFINITY, -INFINITY, -INFINITY, -INFINITY};
#pragma unroll
  for (int half = 0; half < 2; half++) {
    __syncthreads();
    for (int j = tid; j < 2048; j += 256) {
      int row = j >> 3, seg = (j & 7) * 8;
      *(uint4*)&Ks[row][seg] = *(const uint4*)(kg + (half * 256 + row) * 64 + seg);
    }
    __syncthreads();
#pragma unroll
    for (int t = 0; t < 8; t++) {
      float sk = mk_scale(scal[SL_AX_KT + half * 8 + t]);
      float sc = __fmul_rn(__fmul_rn(0.125f, sqv), sk);
#pragma unroll
      for (int h = 0; h < 2; h++) {
        int cbl = t * 2 + h;
        bfx8 b0 = *(const bfx8*)&Ks[cbl * 16 + l16][quad * 8];
        bfx8 b1 = *(const bfx8*)&Ks[cbl * 16 + l16][32 + quad * 8];
        f32x4 acc = {0.f, 0.f, 0.f, 0.f};
        acc = __builtin_amdgcn_mfma_f32_16x16x32_bf16(a0, b0, acc, 0, 0, 0);
        acc = __builtin_amdgcn_mfma_f32_16x16x32_bf16(a1, b1, acc, 0, 0, 0);
        int cb = half * 16 + cbl;
#pragma unroll
        for (int r = 0; r < 4; r++) {
          float sv_ = __fmul_rn(acc[r], sc);
          sreg[cb][r] = sv_;
          rm[r] = fmaxf(rm[r], sv_);
        }
      }
    }
  }
#pragma unroll
  for (int m = 1; m < 16; m <<= 1)
#pragma unroll
    for (int r = 0; r < 4; r++) rm[r] = fmaxf(rm[r], __shfl_xor(rm[r], m));
  float sums[4] = {0.f, 0.f, 0.f, 0.f};
#pragma unroll
  for (int cb = 0; cb < 32; cb++)
#pragma unroll
    for (int r = 0; r < 4; r++) {
      float xc = fixclip(__fsub_rn(sreg[cb][r], rm[r]));
      sums[r] = __fadd_rn(sums[r], pla_fast(xc, tbl));
    }
#pragma unroll
  for (int m = 1; m < 16; m <<= 1)
#pragma unroll
    for (int r = 0; r < 4; r++) sums[r] += __shfl_xor(sums[r], m);
  if (l16 == 0) {
#pragma unroll
    for (int r = 0; r < 4; r++) {
      int row = bh * SS + rowb + quad * 4 + r;
      rowmax[row] = rm[r];
      rowsum[row] = sums[r];
    }
  }
  // one atomicMin per block
  float mn = fminf(fminf(sums[0], sums[1]), fminf(sums[2], sums[3]));
#pragma unroll
  for (int m = 16; m < 64; m <<= 1) mn = fminf(mn, __shfl_xor(mn, m));
  if (lane == 0) redmin[wv] = mn;
  __syncthreads();
  if (tid == 0) {
    mn = fminf(fminf(redmin[0], redmin[1]), fminf(redmin[2], redmin[3]));
    atomicMin((u32*)minslot, __float_as_uint(mn));
  }
}

// pass 2: recompute scores, quantize probs (per-row reciprocal), PV, ctx fp32 [B,S,H*D]
// + fused ctx absmax (1 atomic/block into 8 decontended slots). linear bh-major grid.
__global__ __launch_bounds__(256) void k_attn2(const u16* __restrict__ qq, const u16* __restrict__ kq,
    const u16* __restrict__ vqt, const float* __restrict__ scal, const float* __restrict__ rowmax,
    const float* __restrict__ rowsum, float* __restrict__ ctx, float* __restrict__ ctxax8, PLA pla) {
  __shared__ u16 P[32][520];
  __shared__ float tbl[12][4];
  __shared__ float redmax[4];
  int tid = threadIdx.x;
  if (tid < 12) {
    tbl[tid][0] = pla.a[tid];
    tbl[tid][1] = (tid < 11) ? pla.a[tid + 1] : 1e30f;
    tbl[tid][2] = pla.m[tid];
    tbl[tid][3] = pla.c[tid];
  }
  __syncthreads();
  int blk = blockIdx.x;
  int bh = blk >> 4;
  int q0 = (blk & 15) << 5;
  int wv = tid >> 6, lane = tid & 63, quad = lane >> 4, l16 = lane & 15;
  int rb = (wv >> 1) * 16;
  int cb0 = (wv & 1) * 16;
  const u16* qbase = qq + ((size_t)bh * SS + q0 + rb) * DD;
  const u16* kbase = kq + (size_t)bh * SS * DD;
  bfx8 a0 = *(const bfx8*)(qbase + l16 * DD + quad * 8);
  bfx8 a1 = *(const bfx8*)(qbase + l16 * DD + 32 + quad * 8);
  float sqv = mk_scale(scal[SL_AX_QT + (q0 >> 5)]);
  float minsum = scal[SL_MINSUM];
  float mxsm = pla.c[11] / (minsum + 1e-9f);   // == global max(sm): PLA monotone, every row attains x=0
  float scp = mk_scale(mxsm);
  float rmx[4], inv[4];
#pragma unroll
  for (int r = 0; r < 4; r++) {
    int row = bh * SS + q0 + rb + quad * 4 + r;
    rmx[r] = rowmax[row];
    float t = __fmul_rn(rowsum[row] + 1e-9f, scp);
    inv[r] = 1.0f / t;   // fused (e/rsm)/scp -> e*inv; <=3ulp difference, rint flip ~1e-6/elem
  }
#pragma unroll
  for (int t = 0; t < 8; t++) {
    float sk = mk_scale(scal[SL_AX_KT + (cb0 >> 1) + t]);
    float sc = __fmul_rn(__fmul_rn(0.125f, sqv), sk);
#pragma unroll
    for (int h = 0; h < 2; h++) {
      int cb = cb0 + t * 2 + h;
      const u16* kp = kbase + (size_t)(cb * 16 + l16) * DD + quad * 8;
      bfx8 b0 = *(const bfx8*)kp;
      bfx8 b1 = *(const bfx8*)(kp + 32);
      f32x4 acc = {0.f, 0.f, 0.f, 0.f};
      acc = __builtin_amdgcn_mfma_f32_16x16x32_bf16(a0, b0, acc, 0, 0, 0);
      acc = __builtin_amdgcn_mfma_f32_16x16x32_bf16(a1, b1, acc, 0, 0, 0);
#pragma unroll
      for (int r = 0; r < 4; r++) {
        float sh = __fsub_rn(__fmul_rn(acc[r], sc), rmx[r]);
        float e = pla_fast(fixclip(sh), tbl);
        float np = fminf(fmaxf(rintf(__fmul_rn(e, inv[r])), -127.0f), 127.0f);
        P[rb + quad * 4 + r][cb * 16 + l16] = f2b_exact(np);
      }
    }
  }
  __syncthreads();
  f32x4 acc2[2];
  f32x4 zero = {0.f, 0.f, 0.f, 0.f};
  acc2[0] = zero; acc2[1] = zero;
  const u16* vb = vqt + (size_t)bh * DD * SS;
  int dbase = (wv & 1) * 32;
  int rb2 = (wv >> 1) * 16;
  for (int ks = 0; ks < 16; ks++) {
    bfx8 pa = *(const bfx8*)&P[rb2 + l16][ks * 32 + quad * 8];
#pragma unroll
    for (int j = 0; j < 2; j++) {
      int d = dbase + j * 16 + l16;
      bfx8 vf = *(const bfx8*)(vb + (size_t)d * SS + ks * 32 + quad * 8);
      acc2[j] = __builtin_amdgcn_mfma_f32_16x16x32_bf16(pa, vf, acc2[j], 0, 0, 0);
    }
  }
  float sv = mk_scale(scal[SL_AX_V]);
  float fsc = __fmul_rn(scp, sv);
  int b = bh >> 4, h = bh & 15;
  float cmax = 0.f;
#pragma unroll
  for (int j = 0; j < 2; j++) {
    int d = dbase + j * 16 + l16;
#pragma unroll
    for (int r = 0; r < 4; r++) {
      int srow = q0 + rb2 + quad * 4 + r;
      float cv = __fmul_rn(acc2[j][r], fsc);
      cmax = fmaxf(cmax, fabsf(cv));
      ctx[((size_t)(b * SS + srow)) * HD + h * DD + d] = cv;
    }
  }
#pragma unroll
  for (int m2 = 1; m2 < 64; m2 <<= 1) cmax = fmaxf(cmax, __shfl_xor(cmax, m2));
  if (lane == 0) redmax[wv] = cmax;
  __syncthreads();
  if (tid == 0) {
    cmax = fmaxf(fmaxf(redmax[0], redmax[1]), fmaxf(redmax[2], redmax[3]));
    atomicMax((u32*)&ctxax8[bh & 7], __float_as_uint(cmax));
  }
}

// host: rebuild _build_pla exactly (float64 linspace mirror + degree-1 OLS, cast to f32)
static void build_pla(PLA* p) {
  double xs[1001], ys[1001];
  for (int i = 0; i < 1001; i++) { double t = (double)i * 0.01; xs[i] = t - 10.0; }
  xs[1000] = 0.0;
  for (int i = 0; i < 1001; i++) ys[i] = exp(xs[i]);
  double es = 10.0 / 12.0;
  double edges[13];
  for (int i = 0; i < 13; i++) { double t = (double)i * es; edges[i] = t - 10.0; }
  edges[12] = 0.0;
  for (int k = 0; k < 12; k++) {
    double sx = 0, sy = 0, sxx = 0, sxy = 0; int n = 0;
    for (int j = 0; j < 1001; j++) {
      if (xs[j] >= edges[k] && xs[j] <= edges[k + 1]) {
        n++; sx += xs[j]; sy += ys[j]; sxx += xs[j] * xs[j]; sxy += xs[j] * ys[j];
      }
    }
    double mx = sx / n, my = sy / n;
    double mm = (sxy - sx * my) / (sxx - sx * mx);
    double cc = my - mm * mx;
    p->m[k] = (float)mm; p->c[k] = (float)cc; p->a[k] = (float)edges[k];
  }
}

extern "C" void kernel_launch(void* const* d_in, const int* in_sizes, int n_in,
                              void* d_out, int out_size, void* d_ws, size_t ws_size,
                              hipStream_t stream) {
  const float* hs = (const float*)d_in[0];
  const float* Wq = (const float*)d_in[1]; const float* bq = (const float*)d_in[2];
  const float* Wk = (const float*)d_in[3]; const float* bk = (const float*)d_in[4];
  const float* Wv = (const float*)d_in[5]; const float* bv = (const float*)d_in[6];
  const float* Wo = (const float*)d_in[7]; const float* bo = (const float*)d_in[8];
  float* out = (float*)d_out;
  char* ws = (char*)d_ws;
  float* scal = (float*)ws;                         // 64 scalar slots
  float* sw = (float*)(ws + 4096);                  // 4*1024 per-row weight scales
  float* rowmax = (float*)(ws + (64 << 10));        // 131072 f32
  float* rowsum = (float*)(ws + (576 << 10));       // 131072 f32
  u16* wb = (u16*)(ws + (2ll << 20));               // 4 x [1024,1024] bf16-int
  u16* xq = (u16*)(ws + (10ll << 20));              // [8192,1024] bf16-int (later reused as ctxq)
  u16* qq = (u16*)(ws + (26ll << 20));              // [B,H,S,D]
  u16* kq = (u16*)(ws + (42ll << 20));              // [B,H,S,D]
  u16* vqt = (u16*)(ws + (58ll << 20));             // [B,H,D,S]
  float* tmp = (float*)(ws + (74ll << 20));         // [8192,1024] fp32 temp (q/k/v then ctx)
  u16* ctxq = xq;

  PLA pla;
  build_pla(&pla);

  k_init<<<1, 64, 0, stream>>>(scal);
  k_wprep<<<1024, 256, 0, stream>>>(Wq, sw + 0, wb + 0);
  k_wprep<<<1024, 256, 0, stream>>>(Wk, sw + 1024, wb + 1048576);
  k_wprep<<<1024, 256, 0, stream>>>(Wv, sw + 2048, wb + 2097152);
  k_wprep<<<1024, 256, 0, stream>>>(Wo, sw + 3072, wb + 3145728);
  k_absmax_f32<<<512, 256, 0, stream>>>(hs, NEL, scal + SL_AX_X);
  k_quant_f32<<<1024, 256, 0, stream>>>(hs, xq, scal + SL_AX_X);

  const float* biases[3] = {bq, bk, bv};
  for (int z = 0; z < 3; z++) {
    int axmode = (z < 2) ? 1 : 2;
    float* axslots = (z == 0) ? (scal + SL_AX_QT) : (z == 1) ? (scal + SL_AX_KT) : (scal + SL_AX_V);
    k_gemm<<<dim3(64, 8), 256, 0, stream>>>(xq, wb + (size_t)z * 1048576, scal + SL_AX_X,
                                            sw + z * 1024, biases[z], tmp, (float*)0, 1,
                                            axslots, axmode);
    if (z == 0) {
      k_quant_tiles<<<1024, 256, 0, stream>>>(tmp, qq, scal + SL_AX_QT);
    } else if (z == 1) {
      k_quant_tiles<<<1024, 256, 0, stream>>>(tmp, kq, scal + SL_AX_KT);
    } else {
      k_quant_vT<<<1024, 256, 0, stream>>>(tmp, vqt, scal + SL_AX_V);
    }
  }

  k_attn1<<<2048, 256, 0, stream>>>(qq, kq, scal, scal + SL_MINSUM, rowmax, rowsum, pla);
  k_attn2<<<4096, 256, 0, stream>>>(qq, kq, vqt, scal, rowmax, rowsum, tmp,
                                    scal + SL_AX_CTX8, pla);

  k_quant_ctx<<<1024, 256, 0, stream>>>(tmp, ctxq, scal + SL_AX_CTX8, scal + SL_AX_CTX);
  k_gemm<<<dim3(64, 8), 256, 0, stream>>>(ctxq, wb + 3145728, scal + SL_AX_CTX,
                                          sw + 3072, bo, (float*)0, out, 0,
                                          (float*)0, 0);
}

// Round 7
// 752.321 us; speedup vs baseline: 1.1499x; 1.0152x over previous
//
#include <hip/hip_runtime.h>
#include <math.h>

typedef unsigned short u16;
typedef unsigned int u32;
typedef __bf16 bfx8 __attribute__((ext_vector_type(8)));
typedef float f32x4 __attribute__((ext_vector_type(4)));

#define NB 16
#define SS 512
#define NHD 16
#define DD 64
#define HD 1024
#define NROWS 8192
#define NEL 8388608  // 8192*1024

// scalar slots in ws (floats)
#define SL_AX_X 0
#define SL_AX_V 1
#define SL_MINSUM 2
#define SL_AX_CTX 3
#define SL_AX_QT 4    // 16 slots
#define SL_AX_KT 20   // 16 slots
#define SL_AX_CTX8 36 // 8 slots (decontended ctx absmax)

struct PLA { float m[12]; float c[12]; float a[12]; };

__device__ __forceinline__ float b2f(u16 u) { return __uint_as_float(((u32)u) << 16); }
// exact for integer-valued floats |x|<=127 (low mantissa bits are zero)
__device__ __forceinline__ u16 f2b_exact(float f) { return (u16)(__float_as_uint(f) >> 16); }
__device__ __forceinline__ float mk_scale(float mx) { float s = mx / 127.0f; return (s == 0.0f) ? 1.0f : s; }
__device__ __forceinline__ float quant_val(float x, float s) {
  return fminf(fmaxf(rintf(x / s), -127.0f), 127.0f);
}
__device__ __forceinline__ float fixclip(float sh) {
  float t = rintf(__fmul_rn(sh, 67108864.0f));          // to_fixed_point frac_bits=26
  float fx = __fmul_rn(t, 1.4901161193847656e-08f);     // exact *2^-26
  return fmaxf(fminf(fx, 0.0f), -10.0f);
}
// fast PLA via uniform-interval guess + 1 correction; tbl[i] = {a[i], a[i+1](or 1e30), m[i], c[i]}
// exactly replicates searchsorted(a, xc, 'right')-1 then m*x+c (separate f32 mul+add)
__device__ __forceinline__ float pla_fast(float xc, const float (*tbl)[4]) {
  int idx = (int)floorf(__fmul_rn(__fadd_rn(xc, 10.0f), 1.2f));
  idx = idx < 0 ? 0 : (idx > 11 ? 11 : idx);
  float4 tv = *(const float4*)tbl[idx];
  int up = (xc >= tv.y) ? 1 : 0;       // never true at idx==11 (sentinel 1e30)
  int dn = (xc < tv.x) ? 1 : 0;        // never true at idx==0 (a[0]=-10 <= xc)
  idx += up - dn;
  float4 tv2 = *(const float4*)tbl[idx];
  return __fadd_rn(__fmul_rn(tv2.z, xc), tv2.w);
}

__global__ void k_init(float* scal) {
  int t = threadIdx.x;
  scal[t] = 0.0f;
  if (t == SL_MINSUM) scal[t] = __uint_as_float(0x7f800000u);  // +inf
}

// per-row absmax + quantize one weight matrix row (fp32) -> integer-valued bf16
__global__ void k_wprep(const float* __restrict__ W, float* __restrict__ sw, u16* __restrict__ wout) {
  int r = blockIdx.x;
  int tid = threadIdx.x;
  float4 v = ((const float4*)(W + (size_t)r * 1024))[tid];
  float m = fmaxf(fmaxf(fabsf(v.x), fabsf(v.y)), fmaxf(fabsf(v.z), fabsf(v.w)));
#pragma unroll
  for (int off = 32; off > 0; off >>= 1) m = fmaxf(m, __shfl_down(m, off));
  __shared__ float red[4];
  __shared__ float sbc;
  int lane = tid & 63, wv = tid >> 6;
  if (lane == 0) red[wv] = m;
  __syncthreads();
  if (tid == 0) sbc = mk_scale(fmaxf(fmaxf(red[0], red[1]), fmaxf(red[2], red[3])));
  __syncthreads();
  float s = sbc;
  if (tid == 0) sw[r] = s;
  u16 o0 = f2b_exact(quant_val(v.x, s));
  u16 o1 = f2b_exact(quant_val(v.y, s));
  u16 o2 = f2b_exact(quant_val(v.z, s));
  u16 o3 = f2b_exact(quant_val(v.w, s));
  u32* orow = (u32*)(wout + (size_t)r * 1024);
  orow[tid * 2] = (u32)o0 | ((u32)o1 << 16);
  orow[tid * 2 + 1] = (u32)o2 | ((u32)o3 << 16);
}

__global__ void k_absmax_f32(const float* __restrict__ x, int n, float* slot) {
  int tid = blockIdx.x * blockDim.x + threadIdx.x;
  int stride = gridDim.x * blockDim.x;
  const float4* x4 = (const float4*)x;
  int n4 = n >> 2;
  float m = 0.f;
  for (int j = tid; j < n4; j += stride) {
    float4 v = x4[j];
    m = fmaxf(m, fmaxf(fmaxf(fabsf(v.x), fabsf(v.y)), fmaxf(fabsf(v.z), fabsf(v.w))));
  }
#pragma unroll
  for (int off = 32; off > 0; off >>= 1) m = fmaxf(m, __shfl_down(m, off));
  __shared__ float red[4];
  if ((threadIdx.x & 63) == 0) red[threadIdx.x >> 6] = m;
  __syncthreads();
  if (threadIdx.x == 0) {
    m = fmaxf(fmaxf(red[0], red[1]), fmaxf(red[2], red[3]));
    atomicMax((u32*)slot, __float_as_uint(m));
  }
}

__global__ void k_quant_f32(const float* __restrict__ x, u16* __restrict__ o, const float* __restrict__ slot) {
  float s = mk_scale(*slot);
  int tid = blockIdx.x * blockDim.x + threadIdx.x;
  int stride = gridDim.x * blockDim.x;
  const float4* x4 = (const float4*)x;
  uint2* o2 = (uint2*)o;
  for (int j = tid; j < (NEL >> 2); j += stride) {
    float4 v = x4[j];
    u16 a = f2b_exact(quant_val(v.x, s));
    u16 b = f2b_exact(quant_val(v.y, s));
    u16 c = f2b_exact(quant_val(v.z, s));
    u16 d = f2b_exact(quant_val(v.w, s));
    uint2 w; w.x = (u32)a | ((u32)b << 16); w.y = (u32)c | ((u32)d << 16);
    o2[j] = w;
  }
}

// ctx quant: scale from max of 8 decontended slots; republish folded max for the final gemm
__global__ void k_quant_ctx(const float* __restrict__ x, u16* __restrict__ o,
                            const float* __restrict__ slots8, float* __restrict__ axout) {
  float mx = 0.f;
#pragma unroll
  for (int i = 0; i < 8; i++) mx = fmaxf(mx, slots8[i]);
  float s = mk_scale(mx);
  if (blockIdx.x == 0 && threadIdx.x == 0) *axout = mx;
  int tid = blockIdx.x * blockDim.x + threadIdx.x;
  int stride = gridDim.x * blockDim.x;
  const float4* x4 = (const float4*)x;
  uint2* o2 = (uint2*)o;
  for (int j = tid; j < (NEL >> 2); j += stride) {
    float4 v = x4[j];
    u16 a = f2b_exact(quant_val(v.x, s));
    u16 b = f2b_exact(quant_val(v.y, s));
    u16 c = f2b_exact(quant_val(v.z, s));
    u16 d = f2b_exact(quant_val(v.w, s));
    uint2 w; w.x = (u32)a | ((u32)b << 16); w.y = (u32)c | ((u32)d << 16);
    o2[j] = w;
  }
}

__global__ void k_quant_tiles(const float* __restrict__ x, u16* __restrict__ o, const float* __restrict__ slots) {
  int tid = blockIdx.x * blockDim.x + threadIdx.x;
  int stride = gridDim.x * blockDim.x;
  const float4* x4 = (const float4*)x;
  uint2* o2 = (uint2*)o;
  for (int j = tid; j < (NEL >> 2); j += stride) {
    int e = j << 2;
    float s = mk_scale(slots[(e >> 11) & 15]);
    float4 v = x4[j];
    u16 a = f2b_exact(quant_val(v.x, s));
    u16 b = f2b_exact(quant_val(v.y, s));
    u16 c = f2b_exact(quant_val(v.z, s));
    u16 d = f2b_exact(quant_val(v.w, s));
    uint2 w; w.x = (u32)a | ((u32)b << 16); w.y = (u32)c | ((u32)d << 16);
    o2[j] = w;
  }
}

// quantize v (global scale) and transpose [B,H,S,D] -> [B,H,D,S]
__global__ void k_quant_vT(const float* __restrict__ x, u16* __restrict__ o, const float* __restrict__ slot) {
  __shared__ u16 lds[64][136];
  float s = mk_scale(*slot);
  int bh = blockIdx.x >> 2;
  int sc0 = (blockIdx.x & 3) << 7;  // 128-row s chunk
  const float4* src = (const float4*)(x + ((size_t)bh * SS + sc0) * DD);
  for (int j = threadIdx.x; j < 2048; j += 256) {
    float4 v = src[j];
    int e = j << 2;
    int srow = e >> 6, d = e & 63;
    lds[d][srow] = f2b_exact(quant_val(v.x, s));
    lds[d + 1][srow] = f2b_exact(quant_val(v.y, s));
    lds[d + 2][srow] = f2b_exact(quant_val(v.z, s));
    lds[d + 3][srow] = f2b_exact(quant_val(v.w, s));
  }
  __syncthreads();
  int d = threadIdx.x >> 2, s0 = (threadIdx.x & 3) << 5;
  u16* dst = o + ((size_t)bh * DD + d) * SS + sc0 + s0;
#pragma unroll
  for (int i = 0; i < 32; i += 8)
    *(uint4*)(dst + i) = *(const uint4*)&lds[d][s0 + i];
}

// C[M,N] = A[M,K] * B[N,K]^T  (both integer-valued bf16; exact in fp32 MFMA accum)
// epilogue: val = acc * (sa*sb[n]) + bias[n]; mode1 -> fp32 [B,NH,S,D]; mode0 -> fp32 [M,N]
// axmode: 0 none; 1 per-seq-tile absmax atomics into axslots[16]; 2 global absmax into axslots[0]
__global__ __launch_bounds__(256) void k_gemm(const u16* __restrict__ A, const u16* __restrict__ Bw,
    const float* __restrict__ axslot, const float* __restrict__ sb, const float* __restrict__ bias,
    float* outf, float* outc, int mode, float* axslots, int axmode) {
  __shared__ u16 As[128][72];
  __shared__ u16 Bs[128][72];
  int tid = threadIdx.x;
  int bm = blockIdx.x << 7, bn = blockIdx.y << 7;
  int wv = tid >> 6, lane = tid & 63, quad = lane >> 4, l16 = lane & 15;
  int wr = (wv >> 1) << 6, wc = (wv & 1) << 6;
  int sr = tid >> 1, sseg = (tid & 1) << 5;
  const u16* Ag = A + (size_t)(bm + sr) * 1024 + sseg;
  const u16* Bg = Bw + (size_t)(bn + sr) * 1024 + sseg;
  f32x4 zero = {0.f, 0.f, 0.f, 0.f};
  f32x4 acc[4][4];
#pragma unroll
  for (int i = 0; i < 4; i++)
#pragma unroll
    for (int j = 0; j < 4; j++) acc[i][j] = zero;
  for (int k0 = 0; k0 < 1024; k0 += 64) {
    uint4 av0 = *(const uint4*)(Ag + k0);
    uint4 av1 = *(const uint4*)(Ag + k0 + 8);
    uint4 av2 = *(const uint4*)(Ag + k0 + 16);
    uint4 av3 = *(const uint4*)(Ag + k0 + 24);
    uint4 bv0 = *(const uint4*)(Bg + k0);
    uint4 bv1 = *(const uint4*)(Bg + k0 + 8);
    uint4 bv2 = *(const uint4*)(Bg + k0 + 16);
    uint4 bv3 = *(const uint4*)(Bg + k0 + 24);
    __syncthreads();
    *(uint4*)&As[sr][sseg] = av0;      *(uint4*)&As[sr][sseg + 8] = av1;
    *(uint4*)&As[sr][sseg + 16] = av2; *(uint4*)&As[sr][sseg + 24] = av3;
    *(uint4*)&Bs[sr][sseg] = bv0;      *(uint4*)&Bs[sr][sseg + 8] = bv1;
    *(uint4*)&Bs[sr][sseg + 16] = bv2; *(uint4*)&Bs[sr][sseg + 24] = bv3;
    __syncthreads();
#pragma unroll
    for (int ks = 0; ks < 2; ks++) {
      bfx8 af[4], bfr[4];
#pragma unroll
      for (int i = 0; i < 4; i++) {
        af[i] = *(const bfx8*)&As[wr + i * 16 + l16][ks * 32 + quad * 8];
        bfr[i] = *(const bfx8*)&Bs[wc + i * 16 + l16][ks * 32 + quad * 8];
      }
#pragma unroll
      for (int i = 0; i < 4; i++)
#pragma unroll
        for (int j = 0; j < 4; j++)
          acc[i][j] = __builtin_amdgcn_mfma_f32_16x16x32_bf16(af[i], bfr[j], acc[i][j], 0, 0, 0);
    }
  }
  float sa = mk_scale(*axslot);
  float amax[4] = {0.f, 0.f, 0.f, 0.f};
#pragma unroll
  for (int j = 0; j < 4; j++) {
    int col = bn + wc + j * 16 + l16;
    float sc = __fmul_rn(sa, sb[col]);
    float bi = bias[col];
#pragma unroll
    for (int i = 0; i < 4; i++) {
      int row0 = bm + wr + i * 16 + quad * 4;
#pragma unroll
      for (int r = 0; r < 4; r++) {
        float v = __fadd_rn(__fmul_rn(acc[i][j][r], sc), bi);
        amax[i] = fmaxf(amax[i], fabsf(v));
        int row = row0 + r;
        if (mode) {
          int b = row >> 9, s2 = row & 511, h = col >> 6, d = col & 63;
          outf[((((size_t)b * NHD) + h) * SS + s2) * DD + d] = v;
        } else {
          outc[(size_t)row * HD + col] = v;
        }
      }
    }
  }
  if (axmode == 1) {
    int stile_base = (bm & 511) >> 5;
#pragma unroll
    for (int i = 0; i < 4; i++) {
      float am = amax[i];
#pragma unroll
      for (int m2 = 1; m2 < 64; m2 <<= 1) am = fmaxf(am, __shfl_xor(am, m2));
      if (lane == 0)
        atomicMax((u32*)&axslots[stile_base + ((wr + i * 16) >> 5)], __float_as_uint(am));
    }
  } else if (axmode == 2) {
    float am = fmaxf(fmaxf(amax[0], amax[1]), fmaxf(amax[2], amax[3]));
#pragma unroll
    for (int m2 = 1; m2 < 64; m2 <<= 1) am = fmaxf(am, __shfl_xor(am, m2));
    if (lane == 0) atomicMax((u32*)axslots, __float_as_uint(am));
  }
}

// pass 1: rowmax + PLA row sums in ONE pass (scores held in registers), K staged in LDS halves.
// linear bh-major grid: consecutive blocks share bh -> small concurrent working set per XCD
__global__ __launch_bounds__(256, 2) void k_attn1(const u16* __restrict__ qq, const u16* __restrict__ kq,
    const float* __restrict__ scal, float* __restrict__ minslot,
    float* __restrict__ rowmax, float* __restrict__ rowsum, PLA pla) {
  __shared__ u16 Ks[256][72];        // 36 KB: half of K (256 rows x 64), padded stride
  __shared__ float tbl[12][4];       // {a[i], a[i+1]|1e30, m[i], c[i]}
  __shared__ float redmin[4];
  int tid = threadIdx.x;
  if (tid < 12) {
    tbl[tid][0] = pla.a[tid];
    tbl[tid][1] = (tid < 11) ? pla.a[tid + 1] : 1e30f;
    tbl[tid][2] = pla.m[tid];
    tbl[tid][3] = pla.c[tid];
  }
  int bh = blockIdx.x >> 3;
  int q0 = (blockIdx.x & 7) << 6;
  int wv = tid >> 6, lane = tid & 63, quad = lane >> 4, l16 = lane & 15;
  int rowb = q0 + wv * 16;
  const u16* qbase = qq + ((size_t)bh * SS + rowb) * DD;
  const u16* kg = kq + (size_t)bh * SS * DD;
  bfx8 a0 = *(const bfx8*)(qbase + l16 * DD + quad * 8);
  bfx8 a1 = *(const bfx8*)(qbase + l16 * DD + 32 + quad * 8);
  float sqv = mk_scale(scal[SL_AX_QT + (rowb >> 5)]);
  f32x4 sreg[32];
  float rm[4] = {-INFINITY, -INFINITY, -INFINITY, -INFINITY};
#pragma unroll
  for (int half = 0; half < 2; half++) {
    __syncthreads();
    for (int j = tid; j < 2048; j += 256) {
      int row = j >> 3, seg = (j & 7) * 8;
      *(uint4*)&Ks[row][seg] = *(const uint4*)(kg + (half * 256 + row) * 64 + seg);
    }
    __syncthreads();
#pragma unroll
    for (int t = 0; t < 8; t++) {
      float sk = mk_scale(scal[SL_AX_KT + half * 8 + t]);
      float sc = __fmul_rn(__fmul_rn(0.125f, sqv), sk);
#pragma unroll
      for (int h = 0; h < 2; h++) {
        int cbl = t * 2 + h;
        bfx8 b0 = *(const bfx8*)&Ks[cbl * 16 + l16][quad * 8];
        bfx8 b1 = *(const bfx8*)&Ks[cbl * 16 + l16][32 + quad * 8];
        f32x4 acc = {0.f, 0.f, 0.f, 0.f};
        acc = __builtin_amdgcn_mfma_f32_16x16x32_bf16(a0, b0, acc, 0, 0, 0);
        acc = __builtin_amdgcn_mfma_f32_16x16x32_bf16(a1, b1, acc, 0, 0, 0);
        int cb = half * 16 + cbl;
#pragma unroll
        for (int r = 0; r < 4; r++) {
          float sv_ = __fmul_rn(acc[r], sc);
          sreg[cb][r] = sv_;
          rm[r] = fmaxf(rm[r], sv_);
        }
      }
    }
  }
#pragma unroll
  for (int m = 1; m < 16; m <<= 1)
#pragma unroll
    for (int r = 0; r < 4; r++) rm[r] = fmaxf(rm[r], __shfl_xor(rm[r], m));
  float sums[4] = {0.f, 0.f, 0.f, 0.f};
#pragma unroll
  for (int cb = 0; cb < 32; cb++)
#pragma unroll
    for (int r = 0; r < 4; r++) {
      float xc = fixclip(__fsub_rn(sreg[cb][r], rm[r]));
      sums[r] = __fadd_rn(sums[r], pla_fast(xc, tbl));
    }
#pragma unroll
  for (int m = 1; m < 16; m <<= 1)
#pragma unroll
    for (int r = 0; r < 4; r++) sums[r] += __shfl_xor(sums[r], m);
  if (l16 == 0) {
#pragma unroll
    for (int r = 0; r < 4; r++) {
      int row = bh * SS + rowb + quad * 4 + r;
      rowmax[row] = rm[r];
      rowsum[row] = sums[r];
    }
  }
  // one atomicMin per block
  float mn = fminf(fminf(sums[0], sums[1]), fminf(sums[2], sums[3]));
#pragma unroll
  for (int m = 16; m < 64; m <<= 1) mn = fminf(mn, __shfl_xor(mn, m));
  if (lane == 0) redmin[wv] = mn;
  __syncthreads();
  if (tid == 0) {
    mn = fminf(fminf(redmin[0], redmin[1]), fminf(redmin[2], redmin[3]));
    atomicMin((u32*)minslot, __float_as_uint(mn));
  }
}

// pass 2: K and V staged through LDS (union buffer), P quantized to LDS, PV MFMA.
// linear bh-major grid (working-set locality). Per-element math identical to round-6.
__global__ __launch_bounds__(256) void k_attn2(const u16* __restrict__ qq, const u16* __restrict__ kq,
    const u16* __restrict__ vqt, const float* __restrict__ scal, const float* __restrict__ rowmax,
    const float* __restrict__ rowsum, float* __restrict__ ctx, float* __restrict__ ctxax8, PLA pla) {
  __shared__ union {
    u16 k[128][72];    // one K quarter: 128 k-rows x 64 (+pad)
    u16 v[64][134];    // one V s-quarter: 64 d-rows x 128 s (+pad; 67 dwords, odd -> conflict-free)
  } KV;
  __shared__ u16 P[32][520];
  __shared__ float tbl[12][4];
  __shared__ float redmax[4];
  int tid = threadIdx.x;
  if (tid < 12) {
    tbl[tid][0] = pla.a[tid];
    tbl[tid][1] = (tid < 11) ? pla.a[tid + 1] : 1e30f;
    tbl[tid][2] = pla.m[tid];
    tbl[tid][3] = pla.c[tid];
  }
  int blk = blockIdx.x;
  int bh = blk >> 4;
  int q0 = (blk & 15) << 5;
  int wv = tid >> 6, lane = tid & 63, quad = lane >> 4, l16 = lane & 15;
  int rb = (wv >> 1) * 16;
  int chalf = (wv & 1);                 // which 4-cb slice of each K quarter
  const u16* qbase = qq + ((size_t)bh * SS + q0 + rb) * DD;
  const u16* kg = kq + (size_t)bh * SS * DD;
  bfx8 a0 = *(const bfx8*)(qbase + l16 * DD + quad * 8);
  bfx8 a1 = *(const bfx8*)(qbase + l16 * DD + 32 + quad * 8);
  float sqv = mk_scale(scal[SL_AX_QT + (q0 >> 5)]);
  float minsum = scal[SL_MINSUM];
  float mxsm = pla.c[11] / (minsum + 1e-9f);   // == global max(sm): PLA monotone, every row attains x=0
  float scp = mk_scale(mxsm);
  float rmx[4], inv[4];
#pragma unroll
  for (int r = 0; r < 4; r++) {
    int row = bh * SS + q0 + rb + quad * 4 + r;
    rmx[r] = rowmax[row];
    float t = __fmul_rn(rowsum[row] + 1e-9f, scp);
    inv[r] = 1.0f / t;   // fused (e/rsm)/scp -> e*inv; <=3ulp difference, rint flip ~1e-6/elem
  }
  // ---- QK + P-quant, K staged per 128-row quarter ----
#pragma unroll
  for (int kqtr = 0; kqtr < 4; kqtr++) {
    __syncthreads();
#pragma unroll
    for (int i = 0; i < 4; i++) {
      int idx = tid + i * 256;
      int row = idx >> 3, seg = (idx & 7) * 8;
      *(uint4*)&KV.k[row][seg] = *(const uint4*)(kg + (kqtr * 128 + row) * 64 + seg);
    }
    __syncthreads();
#pragma unroll
    for (int t = 0; t < 4; t++) {
      int cbl = chalf * 4 + t;           // 0..7 within quarter
      int cb = kqtr * 8 + cbl;           // global 0..31
      float sk = mk_scale(scal[SL_AX_KT + (cb >> 1)]);
      float sc = __fmul_rn(__fmul_rn(0.125f, sqv), sk);
      bfx8 b0 = *(const bfx8*)&KV.k[cbl * 16 + l16][quad * 8];
      bfx8 b1 = *(const bfx8*)&KV.k[cbl * 16 + l16][32 + quad * 8];
      f32x4 acc = {0.f, 0.f, 0.f, 0.f};
      acc = __builtin_amdgcn_mfma_f32_16x16x32_bf16(a0, b0, acc, 0, 0, 0);
      acc = __builtin_amdgcn_mfma_f32_16x16x32_bf16(a1, b1, acc, 0, 0, 0);
#pragma unroll
      for (int r = 0; r < 4; r++) {
        float sh = __fsub_rn(__fmul_rn(acc[r], sc), rmx[r]);
        float e = pla_fast(fixclip(sh), tbl);
        float np = fminf(fmaxf(rintf(__fmul_rn(e, inv[r])), -127.0f), 127.0f);
        P[rb + quad * 4 + r][cb * 16 + l16] = f2b_exact(np);
      }
    }
  }
  // ---- PV, V staged per 128-col s-quarter (reuses KV buffer) ----
  f32x4 acc2[2];
  f32x4 zero = {0.f, 0.f, 0.f, 0.f};
  acc2[0] = zero; acc2[1] = zero;
  const u16* vb = vqt + (size_t)bh * DD * SS;
  int dbase = (wv & 1) * 32;
  int rb2 = (wv >> 1) * 16;
#pragma unroll
  for (int sq = 0; sq < 4; sq++) {
    __syncthreads();                      // also guards P completion at sq==0
#pragma unroll
    for (int i = 0; i < 4; i++) {
      int idx = tid + i * 256;
      int row = idx >> 4, seg = (idx & 15) * 8;
      *(uint4*)&KV.v[row][seg] = *(const uint4*)(vb + (size_t)row * SS + sq * 128 + seg);
    }
    __syncthreads();
#pragma unroll
    for (int kl = 0; kl < 4; kl++) {
      int ks = sq * 4 + kl;               // global 0..15 in order: accumulation order unchanged
      bfx8 pa = *(const bfx8*)&P[rb2 + l16][ks * 32 + quad * 8];
#pragma unroll
      for (int j = 0; j < 2; j++) {
        int d = dbase + j * 16 + l16;
        bfx8 vf = *(const bfx8*)&KV.v[d][kl * 32 + quad * 8];
        acc2[j] = __builtin_amdgcn_mfma_f32_16x16x32_bf16(pa, vf, acc2[j], 0, 0, 0);
      }
    }
  }
  float sv = mk_scale(scal[SL_AX_V]);
  float fsc = __fmul_rn(scp, sv);
  int b = bh >> 4, h = bh & 15;
  float cmax = 0.f;
#pragma unroll
  for (int j = 0; j < 2; j++) {
    int d = dbase + j * 16 + l16;
#pragma unroll
    for (int r = 0; r < 4; r++) {
      int srow = q0 + rb2 + quad * 4 + r;
      float cv = __fmul_rn(acc2[j][r], fsc);
      cmax = fmaxf(cmax, fabsf(cv));
      ctx[((size_t)(b * SS + srow)) * HD + h * DD + d] = cv;
    }
  }
#pragma unroll
  for (int m2 = 1; m2 < 64; m2 <<= 1) cmax = fmaxf(cmax, __shfl_xor(cmax, m2));
  if (lane == 0) redmax[wv] = cmax;
  __syncthreads();
  if (tid == 0) {
    cmax = fmaxf(fmaxf(redmax[0], redmax[1]), fmaxf(redmax[2], redmax[3]));
    atomicMax((u32*)&ctxax8[bh & 7], __float_as_uint(cmax));
  }
}

// host: rebuild _build_pla exactly (float64 linspace mirror + degree-1 OLS, cast to f32)
static void build_pla(PLA* p) {
  double xs[1001], ys[1001];
  for (int i = 0; i < 1001; i++) { double t = (double)i * 0.01; xs[i] = t - 10.0; }
  xs[1000] = 0.0;
  for (int i = 0; i < 1001; i++) ys[i] = exp(xs[i]);
  double es = 10.0 / 12.0;
  double edges[13];
  for (int i = 0; i < 13; i++) { double t = (double)i * es; edges[i] = t - 10.0; }
  edges[12] = 0.0;
  for (int k = 0; k < 12; k++) {
    double sx = 0, sy = 0, sxx = 0, sxy = 0; int n = 0;
    for (int j = 0; j < 1001; j++) {
      if (xs[j] >= edges[k] && xs[j] <= edges[k + 1]) {
        n++; sx += xs[j]; sy += ys[j]; sxx += xs[j] * xs[j]; sxy += xs[j] * ys[j];
      }
    }
    double mx = sx / n, my = sy / n;
    double mm = (sxy - sx * my) / (sxx - sx * mx);
    double cc = my - mm * mx;
    p->m[k] = (float)mm; p->c[k] = (float)cc; p->a[k] = (float)edges[k];
  }
}

extern "C" void kernel_launch(void* const* d_in, const int* in_sizes, int n_in,
                              void* d_out, int out_size, void* d_ws, size_t ws_size,
                              hipStream_t stream) {
  const float* hs = (const float*)d_in[0];
  const float* Wq = (const float*)d_in[1]; const float* bq = (const float*)d_in[2];
  const float* Wk = (const float*)d_in[3]; const float* bk = (const float*)d_in[4];
  const float* Wv = (const float*)d_in[5]; const float* bv = (const float*)d_in[6];
  const float* Wo = (const float*)d_in[7]; const float* bo = (const float*)d_in[8];
  float* out = (float*)d_out;
  char* ws = (char*)d_ws;
  float* scal = (float*)ws;                         // 64 scalar slots
  float* sw = (float*)(ws + 4096);                  // 4*1024 per-row weight scales
  float* rowmax = (float*)(ws + (64 << 10));        // 131072 f32
  float* rowsum = (float*)(ws + (576 << 10));       // 131072 f32
  u16* wb = (u16*)(ws + (2ll << 20));               // 4 x [1024,1024] bf16-int
  u16* xq = (u16*)(ws + (10ll << 20));              // [8192,1024] bf16-int (later reused as ctxq)
  u16* qq = (u16*)(ws + (26ll << 20));              // [B,H,S,D]
  u16* kq = (u16*)(ws + (42ll << 20));              // [B,H,S,D]
  u16* vqt = (u16*)(ws + (58ll << 20));             // [B,H,D,S]
  float* tmp = (float*)(ws + (74ll << 20));         // [8192,1024] fp32 temp (q/k/v then ctx)
  u16* ctxq = xq;

  PLA pla;
  build_pla(&pla);

  k_init<<<1, 64, 0, stream>>>(scal);
  k_wprep<<<1024, 256, 0, stream>>>(Wq, sw + 0, wb + 0);
  k_wprep<<<1024, 256, 0, stream>>>(Wk, sw + 1024, wb + 1048576);
  k_wprep<<<1024, 256, 0, stream>>>(Wv, sw + 2048, wb + 2097152);
  k_wprep<<<1024, 256, 0, stream>>>(Wo, sw + 3072, wb + 3145728);
  k_absmax_f32<<<512, 256, 0, stream>>>(hs, NEL, scal + SL_AX_X);
  k_quant_f32<<<1024, 256, 0, stream>>>(hs, xq, scal + SL_AX_X);

  const float* biases[3] = {bq, bk, bv};
  for (int z = 0; z < 3; z++) {
    int axmode = (z < 2) ? 1 : 2;
    float* axslots = (z == 0) ? (scal + SL_AX_QT) : (z == 1) ? (scal + SL_AX_KT) : (scal + SL_AX_V);
    k_gemm<<<dim3(64, 8), 256, 0, stream>>>(xq, wb + (size_t)z * 1048576, scal + SL_AX_X,
                                            sw + z * 1024, biases[z], tmp, (float*)0, 1,
                                            axslots, axmode);
    if (z == 0) {
      k_quant_tiles<<<1024, 256, 0, stream>>>(tmp, qq, scal + SL_AX_QT);
    } else if (z == 1) {
      k_quant_tiles<<<1024, 256, 0, stream>>>(tmp, kq, scal + SL_AX_KT);
    } else {
      k_quant_vT<<<1024, 256, 0, stream>>>(tmp, vqt, scal + SL_AX_V);
    }
  }

  k_attn1<<<2048, 256, 0, stream>>>(qq, kq, scal, scal + SL_MINSUM, rowmax, rowsum, pla);
  k_attn2<<<4096, 256, 0, stream>>>(qq, kq, vqt, scal, rowmax, rowsum, tmp,
                                    scal + SL_AX_CTX8, pla);

  k_quant_ctx<<<1024, 256, 0, stream>>>(tmp, ctxq, scal + SL_AX_CTX8, scal + SL_AX_CTX);
  k_gemm<<<dim3(64, 8), 256, 0, stream>>>(ctxq, wb + 3145728, scal + SL_AX_CTX,
                                          sw + 3072, bo, (float*)0, out, 0,
                                          (float*)0, 0);
}

// Round 8
// 663.055 us; speedup vs baseline: 1.3047x; 1.1346x over previous
//
#include <hip/hip_runtime.h>
#include <math.h>

typedef unsigned short u16;
typedef unsigned int u32;
typedef __bf16 bfx8 __attribute__((ext_vector_type(8)));
typedef float f32x4 __attribute__((ext_vector_type(4)));

#define NB 16
#define SS 512
#define NHD 16
#define DD 64
#define HD 1024
#define NROWS 8192
#define NEL 8388608  // 8192*1024

// scalar slots in ws (floats)
#define SL_AX_X 0
#define SL_AX_V 1
#define SL_MINSUM 2
#define SL_AX_CTX 3
#define SL_AX_QT 4    // 16 slots
#define SL_AX_KT 20   // 16 slots

struct PLA { float m[12]; float c[12]; float a[12]; };

#if __has_builtin(__builtin_amdgcn_global_load_lds)
#define HAVE_GLL 1
#define GLL16(gp, lp) __builtin_amdgcn_global_load_lds( \
    (const __attribute__((address_space(1))) void*)(gp), \
    (__attribute__((address_space(3))) void*)(lp), 16, 0, 0)
#else
#define HAVE_GLL 0
#endif

__device__ __forceinline__ float b2f(u16 u) { return __uint_as_float(((u32)u) << 16); }
// exact for integer-valued floats |x|<=127 (low mantissa bits are zero)
__device__ __forceinline__ u16 f2b_exact(float f) { return (u16)(__float_as_uint(f) >> 16); }
__device__ __forceinline__ float mk_scale(float mx) { float s = mx / 127.0f; return (s == 0.0f) ? 1.0f : s; }
__device__ __forceinline__ float quant_val(float x, float s) {
  return fminf(fmaxf(rintf(x / s), -127.0f), 127.0f);
}
__device__ __forceinline__ float fixclip(float sh) {
  float t = rintf(__fmul_rn(sh, 67108864.0f));          // to_fixed_point frac_bits=26
  float fx = __fmul_rn(t, 1.4901161193847656e-08f);     // exact *2^-26
  return fmaxf(fminf(fx, 0.0f), -10.0f);
}
// fast PLA via uniform-interval guess + 1 correction; tbl[i] = {a[i], a[i+1](or 1e30), m[i], c[i]}
// exactly replicates searchsorted(a, xc, 'right')-1 then m*x+c (separate f32 mul+add)
__device__ __forceinline__ float pla_fast(float xc, const float (*tbl)[4]) {
  int idx = (int)floorf(__fmul_rn(__fadd_rn(xc, 10.0f), 1.2f));
  idx = idx < 0 ? 0 : (idx > 11 ? 11 : idx);
  float4 tv = *(const float4*)tbl[idx];
  int up = (xc >= tv.y) ? 1 : 0;       // never true at idx==11 (sentinel 1e30)
  int dn = (xc < tv.x) ? 1 : 0;        // never true at idx==0 (a[0]=-10 <= xc)
  idx += up - dn;
  float4 tv2 = *(const float4*)tbl[idx];
  return __fadd_rn(__fmul_rn(tv2.z, xc), tv2.w);
}

__global__ void k_init(float* scal) {
  int t = threadIdx.x;
  scal[t] = 0.0f;
  if (t == SL_MINSUM) scal[t] = __uint_as_float(0x7f800000u);  // +inf
}

// per-row absmax + quantize one weight matrix row (fp32) -> integer-valued bf16
__global__ void k_wprep(const float* __restrict__ W, float* __restrict__ sw, u16* __restrict__ wout) {
  int r = blockIdx.x;
  int tid = threadIdx.x;
  float4 v = ((const float4*)(W + (size_t)r * 1024))[tid];
  float m = fmaxf(fmaxf(fabsf(v.x), fabsf(v.y)), fmaxf(fabsf(v.z), fabsf(v.w)));
#pragma unroll
  for (int off = 32; off > 0; off >>= 1) m = fmaxf(m, __shfl_down(m, off));
  __shared__ float red[4];
  __shared__ float sbc;
  int lane = tid & 63, wv = tid >> 6;
  if (lane == 0) red[wv] = m;
  __syncthreads();
  if (tid == 0) sbc = mk_scale(fmaxf(fmaxf(red[0], red[1]), fmaxf(red[2], red[3])));
  __syncthreads();
  float s = sbc;
  if (tid == 0) sw[r] = s;
  u16 o0 = f2b_exact(quant_val(v.x, s));
  u16 o1 = f2b_exact(quant_val(v.y, s));
  u16 o2 = f2b_exact(quant_val(v.z, s));
  u16 o3 = f2b_exact(quant_val(v.w, s));
  u32* orow = (u32*)(wout + (size_t)r * 1024);
  orow[tid * 2] = (u32)o0 | ((u32)o1 << 16);
  orow[tid * 2 + 1] = (u32)o2 | ((u32)o3 << 16);
}

__global__ void k_absmax_f32(const float* __restrict__ x, int n, float* slot) {
  int tid = blockIdx.x * blockDim.x + threadIdx.x;
  int stride = gridDim.x * blockDim.x;
  const float4* x4 = (const float4*)x;
  int n4 = n >> 2;
  float m = 0.f;
  for (int j = tid; j < n4; j += stride) {
    float4 v = x4[j];
    m = fmaxf(m, fmaxf(fmaxf(fabsf(v.x), fabsf(v.y)), fmaxf(fabsf(v.z), fabsf(v.w))));
  }
#pragma unroll
  for (int off = 32; off > 0; off >>= 1) m = fmaxf(m, __shfl_down(m, off));
  __shared__ float red[4];
  if ((threadIdx.x & 63) == 0) red[threadIdx.x >> 6] = m;
  __syncthreads();
  if (threadIdx.x == 0) {
    m = fmaxf(fmaxf(red[0], red[1]), fmaxf(red[2], red[3]));
    atomicMax((u32*)slot, __float_as_uint(m));
  }
}

__global__ void k_quant_f32(const float* __restrict__ x, u16* __restrict__ o, const float* __restrict__ slot) {
  float s = mk_scale(*slot);
  int tid = blockIdx.x * blockDim.x + threadIdx.x;
  int stride = gridDim.x * blockDim.x;
  const float4* x4 = (const float4*)x;
  uint2* o2 = (uint2*)o;
  for (int j = tid; j < (NEL >> 2); j += stride) {
    float4 v = x4[j];
    u16 a = f2b_exact(quant_val(v.x, s));
    u16 b = f2b_exact(quant_val(v.y, s));
    u16 c = f2b_exact(quant_val(v.z, s));
    u16 d = f2b_exact(quant_val(v.w, s));
    uint2 w; w.x = (u32)a | ((u32)b << 16); w.y = (u32)c | ((u32)d << 16);
    o2[j] = w;
  }
}

__global__ void k_quant_tiles(const float* __restrict__ x, u16* __restrict__ o, const float* __restrict__ slots) {
  int tid = blockIdx.x * blockDim.x + threadIdx.x;
  int stride = gridDim.x * blockDim.x;
  const float4* x4 = (const float4*)x;
  uint2* o2 = (uint2*)o;
  for (int j = tid; j < (NEL >> 2); j += stride) {
    int e = j << 2;
    float s = mk_scale(slots[(e >> 11) & 15]);
    float4 v = x4[j];
    u16 a = f2b_exact(quant_val(v.x, s));
    u16 b = f2b_exact(quant_val(v.y, s));
    u16 c = f2b_exact(quant_val(v.z, s));
    u16 d = f2b_exact(quant_val(v.w, s));
    uint2 w; w.x = (u32)a | ((u32)b << 16); w.y = (u32)c | ((u32)d << 16);
    o2[j] = w;
  }
}

// quantize v (global scale) and transpose [B,H,S,D] -> [B,H,D,S]
__global__ void k_quant_vT(const float* __restrict__ x, u16* __restrict__ o, const float* __restrict__ slot) {
  __shared__ u16 lds[64][136];
  float s = mk_scale(*slot);
  int bh = blockIdx.x >> 2;
  int sc0 = (blockIdx.x & 3) << 7;  // 128-row s chunk
  const float4* src = (const float4*)(x + ((size_t)bh * SS + sc0) * DD);
  for (int j = threadIdx.x; j < 2048; j += 256) {
    float4 v = src[j];
    int e = j << 2;
    int srow = e >> 6, d = e & 63;
    lds[d][srow] = f2b_exact(quant_val(v.x, s));
    lds[d + 1][srow] = f2b_exact(quant_val(v.y, s));
    lds[d + 2][srow] = f2b_exact(quant_val(v.z, s));
    lds[d + 3][srow] = f2b_exact(quant_val(v.w, s));
  }
  __syncthreads();
  int d = threadIdx.x >> 2, s0 = (threadIdx.x & 3) << 5;
  u16* dst = o + ((size_t)bh * DD + d) * SS + sc0 + s0;
#pragma unroll
  for (int i = 0; i < 32; i += 8)
    *(uint4*)(dst + i) = *(const uint4*)&lds[d][s0 + i];
}

// C[M,N] = A[M,K] * B[N,K]^T  (both integer-valued bf16; exact in fp32 MFMA accum)
// staging: global_load_lds width-16 into unpadded [128][64] LDS with XOR chunk swizzle
// epilogue: val = acc * (sa*sb[n]) + bias[n]; mode1 -> fp32 [B,NH,S,D]; mode0 -> fp32 [M,N]
// axmode: 0 none; 1 per-seq-tile absmax atomics into axslots[16]; 2 global absmax into axslots[0]
__global__ __launch_bounds__(256) void k_gemm(const u16* __restrict__ A, const u16* __restrict__ Bw,
    const float* __restrict__ axslot, const float* __restrict__ sb, const float* __restrict__ bias,
    float* outf, float* outc, int mode, float* axslots, int axmode) {
  __shared__ u16 As[128][64];
  __shared__ u16 Bs[128][64];
  int tid = threadIdx.x;
  int bm = blockIdx.x << 7, bn = blockIdx.y << 7;
  int wv = tid >> 6, lane = tid & 63, quad = lane >> 4, l16 = lane & 15;
  int wr = (wv >> 1) << 6, wc = (wv & 1) << 6;
  // staging map: wave wv stages rows [wv*32, wv*32+32) in 4 calls of 8 rows;
  // lane l: row offset l>>3, dest chunk l&7, source chunk (l&7)^(l>>3) (XOR swizzle)
  int wrow0 = wv << 5;
  int lrow = lane >> 3, lchunk = lane & 7;
  int gchunk = lchunk ^ lrow;
  const u16* AgL = A + (size_t)(bm + wrow0 + lrow) * 1024 + gchunk * 8;
  const u16* BgL = Bw + (size_t)(bn + wrow0 + lrow) * 1024 + gchunk * 8;
  int sw8 = (l16 & 7);   // fragment-read swizzle component
  f32x4 zero = {0.f, 0.f, 0.f, 0.f};
  f32x4 acc[4][4];
#pragma unroll
  for (int i = 0; i < 4; i++)
#pragma unroll
    for (int j = 0; j < 4; j++) acc[i][j] = zero;
  for (int k0 = 0; k0 < 1024; k0 += 64) {
    __syncthreads();   // previous tile fully consumed
#if HAVE_GLL
#pragma unroll
    for (int c = 0; c < 4; c++) {
      GLL16(AgL + c * 8192 + k0, &As[wrow0 + c * 8][0]);
      GLL16(BgL + c * 8192 + k0, &Bs[wrow0 + c * 8][0]);
    }
#else
#pragma unroll
    for (int c = 0; c < 4; c++) {
      uint4 va = *(const uint4*)(AgL + c * 8192 + k0);
      uint4 vb = *(const uint4*)(BgL + c * 8192 + k0);
      *(uint4*)&As[wrow0 + c * 8 + lrow][lchunk * 8] = va;
      *(uint4*)&Bs[wrow0 + c * 8 + lrow][lchunk * 8] = vb;
    }
#endif
    __syncthreads();   // waits vmcnt(0): staged data visible
#pragma unroll
    for (int ks = 0; ks < 2; ks++) {
      int choff = ((ks * 4 + quad) ^ sw8) * 8;
      bfx8 af[4], bfr[4];
#pragma unroll
      for (int i = 0; i < 4; i++) {
        af[i] = *(const bfx8*)&As[wr + i * 16 + l16][choff];
        bfr[i] = *(const bfx8*)&Bs[wc + i * 16 + l16][choff];
      }
#pragma unroll
      for (int i = 0; i < 4; i++)
#pragma unroll
        for (int j = 0; j < 4; j++)
          acc[i][j] = __builtin_amdgcn_mfma_f32_16x16x32_bf16(af[i], bfr[j], acc[i][j], 0, 0, 0);
    }
  }
  float sa = mk_scale(*axslot);
  float amax[4] = {0.f, 0.f, 0.f, 0.f};
#pragma unroll
  for (int j = 0; j < 4; j++) {
    int col = bn + wc + j * 16 + l16;
    float sc = __fmul_rn(sa, sb[col]);
    float bi = bias[col];
#pragma unroll
    for (int i = 0; i < 4; i++) {
      int row0 = bm + wr + i * 16 + quad * 4;
#pragma unroll
      for (int r = 0; r < 4; r++) {
        float v = __fadd_rn(__fmul_rn(acc[i][j][r], sc), bi);
        amax[i] = fmaxf(amax[i], fabsf(v));
        int row = row0 + r;
        if (mode) {
          int b = row >> 9, s2 = row & 511, h = col >> 6, d = col & 63;
          outf[((((size_t)b * NHD) + h) * SS + s2) * DD + d] = v;
        } else {
          outc[(size_t)row * HD + col] = v;
        }
      }
    }
  }
  if (axmode == 1) {
    int stile_base = (bm & 511) >> 5;
#pragma unroll
    for (int i = 0; i < 4; i++) {
      float am = amax[i];
#pragma unroll
      for (int m2 = 1; m2 < 64; m2 <<= 1) am = fmaxf(am, __shfl_xor(am, m2));
      if (lane == 0)
        atomicMax((u32*)&axslots[stile_base + ((wr + i * 16) >> 5)], __float_as_uint(am));
    }
  } else if (axmode == 2) {
    float am = fmaxf(fmaxf(amax[0], amax[1]), fmaxf(amax[2], amax[3]));
#pragma unroll
    for (int m2 = 1; m2 < 64; m2 <<= 1) am = fmaxf(am, __shfl_xor(am, m2));
    if (lane == 0) atomicMax((u32*)axslots, __float_as_uint(am));
  }
}

// pass 1: rowmax + PLA row sums in ONE pass (scores held in registers), K staged in LDS halves.
// linear bh-major grid: consecutive blocks share bh -> small concurrent working set per XCD
__global__ __launch_bounds__(256, 2) void k_attn1(const u16* __restrict__ qq, const u16* __restrict__ kq,
    const float* __restrict__ scal, float* __restrict__ minslot,
    float* __restrict__ rowmax, float* __restrict__ rowsum, PLA pla) {
  __shared__ u16 Ks[256][72];        // 36 KB: half of K (256 rows x 64), padded stride
  __shared__ float tbl[12][4];       // {a[i], a[i+1]|1e30, m[i], c[i]}
  __shared__ float redmin[4];
  int tid = threadIdx.x;
  if (tid < 12) {
    tbl[tid][0] = pla.a[tid];
    tbl[tid][1] = (tid < 11) ? pla.a[tid + 1] : 1e30f;
    tbl[tid][2] = pla.m[tid];
    tbl[tid][3] = pla.c[tid];
  }
  int bh = blockIdx.x >> 3;
  int q0 = (blockIdx.x & 7) << 6;
  int wv = tid >> 6, lane = tid & 63, quad = lane >> 4, l16 = lane & 15;
  int rowb = q0 + wv * 16;
  const u16* qbase = qq + ((size_t)bh * SS + rowb) * DD;
  const u16* kg = kq + (size_t)bh * SS * DD;
  bfx8 a0 = *(const bfx8*)(qbase + l16 * DD + quad * 8);
  bfx8 a1 = *(const bfx8*)(qbase + l16 * DD + 32 + quad * 8);
  float sqv = mk_scale(scal[SL_AX_QT + (rowb >> 5)]);
  f32x4 sreg[32];
  float rm[4] = {-INFINITY, -INFINITY, -INFINITY, -INFINITY};
#pragma unroll
  for (int half = 0; half < 2; half++) {
    __syncthreads();
    for (int j = tid; j < 2048; j += 256) {
      int row = j >> 3, seg = (j & 7) * 8;
      *(uint4*)&Ks[row][seg] = *(const uint4*)(kg + (half * 256 + row) * 64 + seg);
    }
    __syncthreads();
#pragma unroll
    for (int t = 0; t < 8; t++) {
      float sk = mk_scale(scal[SL_AX_KT + half * 8 + t]);
      float sc = __fmul_rn(__fmul_rn(0.125f, sqv), sk);
#pragma unroll
      for (int h = 0; h < 2; h++) {
        int cbl = t * 2 + h;
        bfx8 b0 = *(const bfx8*)&Ks[cbl * 16 + l16][quad * 8];
        bfx8 b1 = *(const bfx8*)&Ks[cbl * 16 + l16][32 + quad * 8];
        f32x4 acc = {0.f, 0.f, 0.f, 0.f};
        acc = __builtin_amdgcn_mfma_f32_16x16x32_bf16(a0, b0, acc, 0, 0, 0);
        acc = __builtin_amdgcn_mfma_f32_16x16x32_bf16(a1, b1, acc, 0, 0, 0);
        int cb = half * 16 + cbl;
#pragma unroll
        for (int r = 0; r < 4; r++) {
          float sv_ = __fmul_rn(acc[r], sc);
          sreg[cb][r] = sv_;
          rm[r] = fmaxf(rm[r], sv_);
        }
      }
    }
  }
#pragma unroll
  for (int m = 1; m < 16; m <<= 1)
#pragma unroll
    for (int r = 0; r < 4; r++) rm[r] = fmaxf(rm[r], __shfl_xor(rm[r], m));
  float sums[4] = {0.f, 0.f, 0.f, 0.f};
#pragma unroll
  for (int cb = 0; cb < 32; cb++)
#pragma unroll
    for (int r = 0; r < 4; r++) {
      float xc = fixclip(__fsub_rn(sreg[cb][r], rm[r]));
      sums[r] = __fadd_rn(sums[r], pla_fast(xc, tbl));
    }
#pragma unroll
  for (int m = 1; m < 16; m <<= 1)
#pragma unroll
    for (int r = 0; r < 4; r++) sums[r] += __shfl_xor(sums[r], m);
  if (l16 == 0) {
#pragma unroll
    for (int r = 0; r < 4; r++) {
      int row = bh * SS + rowb + quad * 4 + r;
      rowmax[row] = rm[r];
      rowsum[row] = sums[r];
    }
  }
  // one atomicMin per block
  float mn = fminf(fminf(sums[0], sums[1]), fminf(sums[2], sums[3]));
#pragma unroll
  for (int m = 16; m < 64; m <<= 1) mn = fminf(mn, __shfl_xor(mn, m));
  if (lane == 0) redmin[wv] = mn;
  __syncthreads();
  if (tid == 0) {
    mn = fminf(fminf(redmin[0], redmin[1]), fminf(redmin[2], redmin[3]));
    atomicMin((u32*)minslot, __float_as_uint(mn));
  }
}

// pass 2: EXACT restore of the round-4 143-us configuration (per-element divisions,
// direct global K/V reads, no fused absmax tail). linear bh-major grid.
__global__ __launch_bounds__(256) void k_attn2(const u16* __restrict__ qq, const u16* __restrict__ kq,
    const u16* __restrict__ vqt, const float* __restrict__ scal, const float* __restrict__ rowmax,
    const float* __restrict__ rowsum, float* __restrict__ ctx, PLA pla) {
  __shared__ u16 P[32][520];
  __shared__ float tbl[12][4];
  int tid = threadIdx.x;
  if (tid < 12) {
    tbl[tid][0] = pla.a[tid];
    tbl[tid][1] = (tid < 11) ? pla.a[tid + 1] : 1e30f;
    tbl[tid][2] = pla.m[tid];
    tbl[tid][3] = pla.c[tid];
  }
  __syncthreads();
  int blk = blockIdx.x;
  int bh = blk >> 4;
  int q0 = (blk & 15) << 5;
  int wv = tid >> 6, lane = tid & 63, quad = lane >> 4, l16 = lane & 15;
  int rb = (wv >> 1) * 16;
  int cb0 = (wv & 1) * 16;
  const u16* qbase = qq + ((size_t)bh * SS + q0 + rb) * DD;
  const u16* kbase = kq + (size_t)bh * SS * DD;
  bfx8 a0 = *(const bfx8*)(qbase + l16 * DD + quad * 8);
  bfx8 a1 = *(const bfx8*)(qbase + l16 * DD + 32 + quad * 8);
  float sqv = mk_scale(scal[SL_AX_QT + (q0 >> 5)]);
  float rmx[4], rsm[4];
#pragma unroll
  for (int r = 0; r < 4; r++) {
    int row = bh * SS + q0 + rb + quad * 4 + r;
    rmx[r] = rowmax[row];
    rsm[r] = rowsum[row] + 1e-9f;
  }
  float minsum = scal[SL_MINSUM];
  float mxsm = pla.c[11] / (minsum + 1e-9f);   // == global max(sm): PLA monotone, every row attains x=0
  float scp = mk_scale(mxsm);
#pragma unroll
  for (int t = 0; t < 8; t++) {
    float sk = mk_scale(scal[SL_AX_KT + (cb0 >> 1) + t]);
    float sc = __fmul_rn(__fmul_rn(0.125f, sqv), sk);
#pragma unroll
    for (int h = 0; h < 2; h++) {
      int cb = cb0 + t * 2 + h;
      const u16* kp = kbase + (size_t)(cb * 16 + l16) * DD + quad * 8;
      bfx8 b0 = *(const bfx8*)kp;
      bfx8 b1 = *(const bfx8*)(kp + 32);
      f32x4 acc = {0.f, 0.f, 0.f, 0.f};
      acc = __builtin_amdgcn_mfma_f32_16x16x32_bf16(a0, b0, acc, 0, 0, 0);
      acc = __builtin_amdgcn_mfma_f32_16x16x32_bf16(a1, b1, acc, 0, 0, 0);
#pragma unroll
      for (int r = 0; r < 4; r++) {
        float sh = __fsub_rn(__fmul_rn(acc[r], sc), rmx[r]);
        float e = pla_fast(fixclip(sh), tbl);
        float smv = e / rsm[r];
        float np = fminf(fmaxf(rintf(smv / scp), -127.0f), 127.0f);
        P[rb + quad * 4 + r][cb * 16 + l16] = f2b_exact(np);
      }
    }
  }
  __syncthreads();
  f32x4 acc2[2];
  f32x4 zero = {0.f, 0.f, 0.f, 0.f};
  acc2[0] = zero; acc2[1] = zero;
  const u16* vb = vqt + (size_t)bh * DD * SS;
  int dbase = (wv & 1) * 32;
  int rb2 = (wv >> 1) * 16;
  for (int ks = 0; ks < 16; ks++) {
    bfx8 pa = *(const bfx8*)&P[rb2 + l16][ks * 32 + quad * 8];
#pragma unroll
    for (int j = 0; j < 2; j++) {
      int d = dbase + j * 16 + l16;
      bfx8 vf = *(const bfx8*)(vb + (size_t)d * SS + ks * 32 + quad * 8);
      acc2[j] = __builtin_amdgcn_mfma_f32_16x16x32_bf16(pa, vf, acc2[j], 0, 0, 0);
    }
  }
  float sv = mk_scale(scal[SL_AX_V]);
  float fsc = __fmul_rn(scp, sv);
  int b = bh >> 4, h = bh & 15;
#pragma unroll
  for (int j = 0; j < 2; j++) {
    int d = dbase + j * 16 + l16;
#pragma unroll
    for (int r = 0; r < 4; r++) {
      int srow = q0 + rb2 + quad * 4 + r;
      ctx[((size_t)(b * SS + srow)) * HD + h * DD + d] = __fmul_rn(acc2[j][r], fsc);
    }
  }
}

// host: rebuild _build_pla exactly (float64 linspace mirror + degree-1 OLS, cast to f32)
static void build_pla(PLA* p) {
  double xs[1001], ys[1001];
  for (int i = 0; i < 1001; i++) { double t = (double)i * 0.01; xs[i] = t - 10.0; }
  xs[1000] = 0.0;
  for (int i = 0; i < 1001; i++) ys[i] = exp(xs[i]);
  double es = 10.0 / 12.0;
  double edges[13];
  for (int i = 0; i < 13; i++) { double t = (double)i * es; edges[i] = t - 10.0; }
  edges[12] = 0.0;
  for (int k = 0; k < 12; k++) {
    double sx = 0, sy = 0, sxx = 0, sxy = 0; int n = 0;
    for (int j = 0; j < 1001; j++) {
      if (xs[j] >= edges[k] && xs[j] <= edges[k + 1]) {
        n++; sx += xs[j]; sy += ys[j]; sxx += xs[j] * xs[j]; sxy += xs[j] * ys[j];
      }
    }
    double mx = sx / n, my = sy / n;
    double mm = (sxy - sx * my) / (sxx - sx * mx);
    double cc = my - mm * mx;
    p->m[k] = (float)mm; p->c[k] = (float)cc; p->a[k] = (float)edges[k];
  }
}

extern "C" void kernel_launch(void* const* d_in, const int* in_sizes, int n_in,
                              void* d_out, int out_size, void* d_ws, size_t ws_size,
                              hipStream_t stream) {
  const float* hs = (const float*)d_in[0];
  const float* Wq = (const float*)d_in[1]; const float* bq = (const float*)d_in[2];
  const float* Wk = (const float*)d_in[3]; const float* bk = (const float*)d_in[4];
  const float* Wv = (const float*)d_in[5]; const float* bv = (const float*)d_in[6];
  const float* Wo = (const float*)d_in[7]; const float* bo = (const float*)d_in[8];
  float* out = (float*)d_out;
  char* ws = (char*)d_ws;
  float* scal = (float*)ws;                         // 64 scalar slots
  float* sw = (float*)(ws + 4096);                  // 4*1024 per-row weight scales
  float* rowmax = (float*)(ws + (64 << 10));        // 131072 f32
  float* rowsum = (float*)(ws + (576 << 10));       // 131072 f32
  u16* wb = (u16*)(ws + (2ll << 20));               // 4 x [1024,1024] bf16-int
  u16* xq = (u16*)(ws + (10ll << 20));              // [8192,1024] bf16-int (later reused as ctxq)
  u16* qq = (u16*)(ws + (26ll << 20));              // [B,H,S,D]
  u16* kq = (u16*)(ws + (42ll << 20));              // [B,H,S,D]
  u16* vqt = (u16*)(ws + (58ll << 20));             // [B,H,D,S]
  float* tmp = (float*)(ws + (74ll << 20));         // [8192,1024] fp32 temp (q/k/v then ctx)
  u16* ctxq = xq;

  PLA pla;
  build_pla(&pla);

  k_init<<<1, 64, 0, stream>>>(scal);
  k_wprep<<<1024, 256, 0, stream>>>(Wq, sw + 0, wb + 0);
  k_wprep<<<1024, 256, 0, stream>>>(Wk, sw + 1024, wb + 1048576);
  k_wprep<<<1024, 256, 0, stream>>>(Wv, sw + 2048, wb + 2097152);
  k_wprep<<<1024, 256, 0, stream>>>(Wo, sw + 3072, wb + 3145728);
  k_absmax_f32<<<512, 256, 0, stream>>>(hs, NEL, scal + SL_AX_X);
  k_quant_f32<<<1024, 256, 0, stream>>>(hs, xq, scal + SL_AX_X);

  const float* biases[3] = {bq, bk, bv};
  for (int z = 0; z < 3; z++) {
    int axmode = (z < 2) ? 1 : 2;
    float* axslots = (z == 0) ? (scal + SL_AX_QT) : (z == 1) ? (scal + SL_AX_KT) : (scal + SL_AX_V);
    k_gemm<<<dim3(64, 8), 256, 0, stream>>>(xq, wb + (size_t)z * 1048576, scal + SL_AX_X,
                                            sw + z * 1024, biases[z], tmp, (float*)0, 1,
                                            axslots, axmode);
    if (z == 0) {
      k_quant_tiles<<<1024, 256, 0, stream>>>(tmp, qq, scal + SL_AX_QT);
    } else if (z == 1) {
      k_quant_tiles<<<1024, 256, 0, stream>>>(tmp, kq, scal + SL_AX_KT);
    } else {
      k_quant_vT<<<1024, 256, 0, stream>>>(tmp, vqt, scal + SL_AX_V);
    }
  }

  k_attn1<<<2048, 256, 0, stream>>>(qq, kq, scal, scal + SL_MINSUM, rowmax, rowsum, pla);
  k_attn2<<<4096, 256, 0, stream>>>(qq, kq, vqt, scal, rowmax, rowsum, tmp, pla);

  k_absmax_f32<<<512, 256, 0, stream>>>(tmp, NEL, scal + SL_AX_CTX);
  k_quant_f32<<<1024, 256, 0, stream>>>(tmp, ctxq, scal + SL_AX_CTX);
  k_gemm<<<dim3(64, 8), 256, 0, stream>>>(ctxq, wb + 3145728, scal + SL_AX_CTX,
                                          sw + 3072, bo, (float*)0, out, 0,
                                          (float*)0, 0);
}